// Round 1
// baseline (308.144 us; speedup 1.0000x reference)
//
#include <hip/hip_runtime.h>
#include <math.h>

#define TT 2
#define CH 128
#define HH 96
#define WW 96
#define HWS 9216            // H*W
#define QTOT 18432          // T*H*W
#define QC (QTOT*CH)        // elems per [p][c] buffer
#define HEADS 4
#define HD 32
#define WSZ 8
#define KTOP 16
#define SCALE 0.17677669529663687f  // 32^-0.5

// ---------------- depthwise 3x3 (zero-pad SAME), out layout [qkv][c][p] ----------------
__global__ __launch_bounds__(256) void dw_kernel(
    const float* __restrict__ x,
    const float* __restrict__ wq, const float* __restrict__ wk, const float* __restrict__ wv,
    float* __restrict__ t_dw)
{
    int sel = blockIdx.y;
    const float* wdw = sel == 0 ? wq : (sel == 1 ? wk : wv);
    int tid = blockIdx.x * 256 + threadIdx.x;   // 0 .. 3*... grid exact
    int hw = tid % HWS;
    int cf = tid / HWS;         // 0..255
    int c = cf & (CH - 1);
    int tt = cf >> 7;
    int i = hw / WW, j = hw % WW;
    const float* xp = x + (size_t)(tt * CH + c) * HWS;
    float w[9];
#pragma unroll
    for (int r = 0; r < 9; r++) w[r] = wdw[c * 9 + r];
    float s = 0.f;
#pragma unroll
    for (int r = 0; r < 3; r++) {
        int ii = i + r - 1;
        if (ii < 0 || ii >= HH) continue;
#pragma unroll
        for (int ss = 0; ss < 3; ss++) {
            int jj = j + ss - 1;
            if (jj < 0 || jj >= WW) continue;
            s += xp[ii * WW + jj] * w[r * 3 + ss];
        }
    }
    t_dw[(size_t)sel * QC + (size_t)c * QTOT + tt * HWS + hw] = s;
}

// ---------------- pointwise GEMM: out[p][o] = sum_c W[o][c]*t[c][p] + b[o]  (q scaled) ----
__global__ __launch_bounds__(256) void gemm_qkv_kernel(
    const float* __restrict__ t_dw,
    const float* __restrict__ wq_pw, const float* __restrict__ bq,
    const float* __restrict__ wk_pw, const float* __restrict__ bk,
    const float* __restrict__ wv_pw, const float* __restrict__ bv,
    float* __restrict__ out)
{
    int sel = blockIdx.y;
    const float* Wg = sel == 0 ? wq_pw : (sel == 1 ? wk_pw : wv_pw);
    const float* bg = sel == 0 ? bq : (sel == 1 ? bk : bv);
    const float* A = t_dw + (size_t)sel * QC;   // [c][p]
    float* O = out + (size_t)sel * QC;          // [p][c]
    float scale = sel == 0 ? SCALE : 1.f;

    __shared__ float t_s[32][64];
    __shared__ float W_s[128][33];   // [o][cc] padded: conflict-free stage + read
    int tid = threadIdx.x;
    int o_grp = tid & 31;            // o = o_grp + 32*i
    int p_grp = tid >> 5;            // p = pbase + p_grp*8 + i
    int pbase = blockIdx.x * 64;
    float acc[8][4] = {};

    for (int c0 = 0; c0 < CH; c0 += 32) {
#pragma unroll
        for (int r = 0; r < 8; r++) {
            int lin = r * 256 + tid;
            int cc = lin >> 6, pp = lin & 63;
            t_s[cc][pp] = A[(size_t)(c0 + cc) * QTOT + pbase + pp];
        }
#pragma unroll
        for (int r = 0; r < 16; r++) {
            int lin = r * 256 + tid;
            int cc = lin & 31, oo = lin >> 5;
            W_s[oo][cc] = Wg[oo * CH + c0 + cc];
        }
        __syncthreads();
#pragma unroll 4
        for (int cc = 0; cc < 32; cc++) {
            float a[8];
#pragma unroll
            for (int i = 0; i < 8; i++) a[i] = t_s[cc][p_grp * 8 + i];
            float b[4];
#pragma unroll
            for (int i = 0; i < 4; i++) b[i] = W_s[o_grp + 32 * i][cc];
#pragma unroll
            for (int i = 0; i < 8; i++)
#pragma unroll
                for (int k = 0; k < 4; k++) acc[i][k] += a[i] * b[k];
        }
        __syncthreads();
    }
#pragma unroll
    for (int k = 0; k < 4; k++) {
        int o = o_grp + 32 * k;
        float bb = bg[o];
#pragma unroll
        for (int i = 0; i < 8; i++) {
            int p = pbase + p_grp * 8 + i;
            O[(size_t)p * CH + o] = (acc[i][k] + bb) * scale;
        }
    }
}

// ---------------- attention: one wave per (pixel, head) ----------------
__device__ __forceinline__ int refl(int x, int n) {
    x = x < 0 ? -x : x;
    return x >= n ? 2 * (n - 1) - x : x;
}

__global__ __launch_bounds__(256) void attn_kernel(
    const float* __restrict__ q,   // [p][128]
    const float* __restrict__ k,
    const float* __restrict__ v,
    float* __restrict__ att)       // [p][128]
{
    int p = blockIdx.x;
    int h = threadIdx.x >> 6;      // head = wave id
    int lane = threadIdx.x & 63;

    int hw = p % HWS;
    int tt = p / HWS;
    int i = hw / WW, j = hw % WW;
    int di = (lane >> 3) - 4;
    int dj = (lane & 7) - 4;
    int ni = refl(i + di, HH);
    int nj = refl(j + dj, WW);
    int pix = tt * HWS + ni * WW + nj;

    const float* qp = q + (size_t)p * CH + h * HD;
    const float* kp = k + (size_t)pix * CH + h * HD;
    float dist = 0.f;
#pragma unroll
    for (int d = 0; d < HD; d += 4) {
        float4 qv = *(const float4*)(qp + d);
        float4 kv = *(const float4*)(kp + d);
        dist += qv.x * kv.x + qv.y * kv.y + qv.z * kv.z + qv.w * kv.w;
    }

    // 64-lane bitonic sort, key = (val desc, idx asc) — matches top_k tie-break
    float val = dist;
    int idx = lane;
#pragma unroll
    for (int kk = 2; kk <= 64; kk <<= 1) {
#pragma unroll
        for (int jj = kk >> 1; jj > 0; jj >>= 1) {
            float o_val = __shfl_xor(val, jj);
            int o_idx = __shfl_xor(idx, jj);
            bool takeBetter = (((lane & kk) != 0) == ((lane & jj) != 0));
            bool mineBetter = (val > o_val) || (val == o_val && idx < o_idx);
            if (takeBetter != mineBetter) { val = o_val; idx = o_idx; }
        }
    }
    // lane r holds r-th best (r=0 max). Recompute selected pixel from idx.
    int sdi = (idx >> 3) - 4;
    int sdj = (idx & 7) - 4;
    int spix = tt * HWS + refl(i + sdi, HH) * WW + refl(j + sdj, WW);

    float m = __shfl(val, 0);
    float e = (lane < KTOP) ? expf(val - m) : 0.f;
    float denom = e;
#pragma unroll
    for (int s = 1; s < 64; s <<= 1) denom += __shfl_xor(denom, s);

    const int d = lane & (HD - 1);
    float acc = 0.f;
#pragma unroll
    for (int r = 0; r < KTOP; r++) {
        float ar = __shfl(e, r);
        int pr = __shfl(spix, r);
        acc += ar * v[(size_t)pr * CH + h * HD + d];
    }
    if (lane < HD) att[(size_t)p * CH + h * HD + lane] = acc / denom;
}

// ---------------- proj GEMM: out[t][o][hw] = sum_c A[p][c]*Wp[o][c] + bp[o] -------------
__global__ __launch_bounds__(256) void proj_kernel(
    const float* __restrict__ A,     // [p][128]
    const float* __restrict__ Wp,    // [o][c]
    const float* __restrict__ bp,
    float* __restrict__ out)         // NCHW
{
    __shared__ float t_s[32][66];    // pad 66: conflict-free transpose-stage, float2 reads
    __shared__ float W_s[128][33];
    int tid = threadIdx.x;
    int o_grp = tid & 31;
    int p_grp = tid >> 5;
    int pbase = blockIdx.x * 64;
    float acc[8][4] = {};

    for (int c0 = 0; c0 < CH; c0 += 32) {
#pragma unroll
        for (int r = 0; r < 8; r++) {
            int lin = r * 256 + tid;
            int cc = lin & 31, pp = lin >> 5;
            t_s[cc][pp] = A[(size_t)(pbase + pp) * CH + c0 + cc];
        }
#pragma unroll
        for (int r = 0; r < 16; r++) {
            int lin = r * 256 + tid;
            int cc = lin & 31, oo = lin >> 5;
            W_s[oo][cc] = Wp[oo * CH + c0 + cc];
        }
        __syncthreads();
#pragma unroll 4
        for (int cc = 0; cc < 32; cc++) {
            float a[8];
#pragma unroll
            for (int i = 0; i < 8; i++) a[i] = t_s[cc][p_grp * 8 + i];
            float b[4];
#pragma unroll
            for (int i = 0; i < 4; i++) b[i] = W_s[o_grp + 32 * i][cc];
#pragma unroll
            for (int i = 0; i < 8; i++)
#pragma unroll
                for (int kq = 0; kq < 4; kq++) acc[i][kq] += a[i] * b[kq];
        }
        __syncthreads();
    }
#pragma unroll
    for (int kq = 0; kq < 4; kq++) {
        int o = o_grp + 32 * kq;
        float bb = bp[o];
#pragma unroll
        for (int i = 0; i < 8; i++) {
            int p = pbase + p_grp * 8 + i;
            int hw = p % HWS, tt = p / HWS;
            out[((size_t)(tt * CH + o)) * HWS + hw] = acc[i][kq] + bb;
        }
    }
}

extern "C" void kernel_launch(void* const* d_in, const int* in_sizes, int n_in,
                              void* d_out, int out_size, void* d_ws, size_t ws_size,
                              hipStream_t stream) {
    const float* vid    = (const float*)d_in[0];
    const float* wq_dw  = (const float*)d_in[1];
    const float* wq_pw  = (const float*)d_in[2];
    const float* bq     = (const float*)d_in[3];
    const float* wk_dw  = (const float*)d_in[4];
    const float* wk_pw  = (const float*)d_in[5];
    const float* bk     = (const float*)d_in[6];
    const float* wv_dw  = (const float*)d_in[7];
    const float* wv_pw  = (const float*)d_in[8];
    const float* bv     = (const float*)d_in[9];
    const float* proj_w = (const float*)d_in[10];
    const float* proj_b = (const float*)d_in[11];
    float* out = (float*)d_out;

    float* t_dw = (float*)d_ws;                 // 3 * QC  (dw results, [c][p])
    float* qkv  = t_dw + (size_t)3 * QC;        // 3 * QC  (q,k,v, [p][c])
    float* att  = qkv + (size_t)3 * QC;         // QC      ([p][c])

    dw_kernel<<<dim3(QTOT * CH / 256, 3), 256, 0, stream>>>(vid, wq_dw, wk_dw, wv_dw, t_dw);
    gemm_qkv_kernel<<<dim3(QTOT / 64, 3), 256, 0, stream>>>(
        t_dw, wq_pw, bq, wk_pw, bk, wv_pw, bv, qkv);
    attn_kernel<<<QTOT, 256, 0, stream>>>(qkv, qkv + QC, qkv + (size_t)2 * QC, att);
    proj_kernel<<<QTOT / 64, 256, 0, stream>>>(att, proj_w, proj_b, out);
}

// Round 2
// 280.545 us; speedup vs baseline: 1.0984x; 1.0984x over previous
//
#include <hip/hip_runtime.h>
#include <math.h>

#define TT 2
#define CH 128
#define HH 96
#define WW 96
#define HWS 9216            // H*W
#define QTOT 18432          // T*H*W
#define QC (QTOT*CH)
#define HD 32
#define KTOP 16
#define SCALE 0.17677669529663687f  // 32^-0.5

typedef __attribute__((ext_vector_type(8))) short short8;
typedef __attribute__((ext_vector_type(4))) float floatx4;

__device__ __forceinline__ unsigned short f2bf(float f) {
    union { float f; unsigned u; } x; x.f = f;
    unsigned r = x.u + 0x7fffu + ((x.u >> 16) & 1u);
    return (unsigned short)(r >> 16);
}

// ---------------- depthwise 3x3 (zero-pad SAME), out fp32 [sel][c][p] ----------------
__global__ __launch_bounds__(256) void dw_kernel(
    const float* __restrict__ x,
    const float* __restrict__ wq, const float* __restrict__ wk, const float* __restrict__ wv,
    float* __restrict__ t_dw)
{
    int sel = blockIdx.y;
    const float* wdw = sel == 0 ? wq : (sel == 1 ? wk : wv);
    int tid = blockIdx.x * 256 + threadIdx.x;
    int hw = tid % HWS;
    int cf = tid / HWS;
    int c = cf & (CH - 1);
    int tt = cf >> 7;
    int i = hw / WW, j = hw % WW;
    const float* xp = x + (size_t)(tt * CH + c) * HWS;
    float w[9];
#pragma unroll
    for (int r = 0; r < 9; r++) w[r] = wdw[c * 9 + r];
    float s = 0.f;
#pragma unroll
    for (int r = 0; r < 3; r++) {
        int ii = i + r - 1;
        if (ii < 0 || ii >= HH) continue;
#pragma unroll
        for (int ss = 0; ss < 3; ss++) {
            int jj = j + ss - 1;
            if (jj < 0 || jj >= WW) continue;
            s += xp[ii * WW + jj] * w[r * 3 + ss];
        }
    }
    t_dw[(size_t)sel * QC + (size_t)c * QTOT + tt * HWS + hw] = s;
}

// ---------------- transpose+convert v: [c][p] fp32 -> [p][c] bf16 ----------------
__global__ __launch_bounds__(256) void transcvt_v(
    const float* __restrict__ vd, unsigned short* __restrict__ vb)
{
    __shared__ float s[64][33];
    int t = threadIdx.x;
    int p0 = blockIdx.x * 64;
    int c0 = blockIdx.y * 32;
#pragma unroll
    for (int r = 0; r < 2; r++) {
        int lin = r * 256 + t;
        int c = lin >> 4;        // 0..31
        int pq = lin & 15;
        float4 v4 = *(const float4*)(vd + (size_t)(c0 + c) * QTOT + p0 + pq * 4);
        s[pq * 4 + 0][c] = v4.x; s[pq * 4 + 1][c] = v4.y;
        s[pq * 4 + 2][c] = v4.z; s[pq * 4 + 3][c] = v4.w;
    }
    __syncthreads();
    int p = t >> 2, cq = t & 3;
    unsigned u[8];
#pragma unroll
    for (int j = 0; j < 8; j++) u[j] = f2bf(s[p][cq * 8 + j]);
    uint4 pack;
    pack.x = u[0] | (u[1] << 16); pack.y = u[2] | (u[3] << 16);
    pack.z = u[4] | (u[5] << 16); pack.w = u[6] | (u[7] << 16);
    *(uint4*)(vb + (size_t)(p0 + p) * CH + c0 + cq * 8) = pack;
}

// ---------------- fp32 pointwise GEMM for q,k only (bit-identical to round 1) ----------
__global__ __launch_bounds__(256) void gemm_qk_kernel(
    const float* __restrict__ t_dw,
    const float* __restrict__ wq_pw, const float* __restrict__ bq,
    const float* __restrict__ wk_pw, const float* __restrict__ bk,
    float* __restrict__ out)
{
    int sel = blockIdx.y;   // 0=q, 1=k
    const float* Wg = sel == 0 ? wq_pw : wk_pw;
    const float* bg = sel == 0 ? bq : bk;
    const float* A = t_dw + (size_t)sel * QC;   // [c][p]
    float* O = out + (size_t)sel * QC;          // [p][c]
    float scale = sel == 0 ? SCALE : 1.f;

    __shared__ float t_s[32][64];
    __shared__ float W_s[128][33];
    int tid = threadIdx.x;
    int o_grp = tid & 31;
    int p_grp = tid >> 5;
    int pbase = blockIdx.x * 64;
    float acc[8][4] = {};

    for (int c0 = 0; c0 < CH; c0 += 32) {
#pragma unroll
        for (int r = 0; r < 8; r++) {
            int lin = r * 256 + tid;
            int cc = lin >> 6, pp = lin & 63;
            t_s[cc][pp] = A[(size_t)(c0 + cc) * QTOT + pbase + pp];
        }
#pragma unroll
        for (int r = 0; r < 16; r++) {
            int lin = r * 256 + tid;
            int cc = lin & 31, oo = lin >> 5;
            W_s[oo][cc] = Wg[oo * CH + c0 + cc];
        }
        __syncthreads();
#pragma unroll 4
        for (int cc = 0; cc < 32; cc++) {
            float a[8];
#pragma unroll
            for (int i = 0; i < 8; i++) a[i] = t_s[cc][p_grp * 8 + i];
            float b[4];
#pragma unroll
            for (int i = 0; i < 4; i++) b[i] = W_s[o_grp + 32 * i][cc];
#pragma unroll
            for (int i = 0; i < 8; i++)
#pragma unroll
                for (int k = 0; k < 4; k++) acc[i][k] += a[i] * b[k];
        }
        __syncthreads();
    }
#pragma unroll
    for (int k = 0; k < 4; k++) {
        int o = o_grp + 32 * k;
        float bb = bg[o];
#pragma unroll
        for (int i = 0; i < 8; i++) {
            int p = pbase + p_grp * 8 + i;
            O[(size_t)p * CH + o] = (acc[i][k] + bb) * scale;
        }
    }
}

// ---------------- v pointwise via bf16 MFMA: O[p][o] = sum_c A[p][c] W[o][c] + b ---------
__global__ __launch_bounds__(256) void vgemm_mfma(
    const unsigned short* __restrict__ A,   // v_bf [p][c] bf16
    const float* __restrict__ W,            // [o][c] fp32
    const float* __restrict__ bias,
    float* __restrict__ O)                  // fp32 [p][c]
{
    __shared__ unsigned short Ws[128 * 136];
    int t = threadIdx.x;
#pragma unroll
    for (int r = 0; r < 16; r++) {
        int lin = r * 256 + t;
        int o = lin >> 5, cq = lin & 31;
        float4 w4 = *(const float4*)(W + o * CH + cq * 4);
        uint2 pk;
        pk.x = f2bf(w4.x) | ((unsigned)f2bf(w4.y) << 16);
        pk.y = f2bf(w4.z) | ((unsigned)f2bf(w4.w) << 16);
        *(uint2*)(&Ws[o * 136 + cq * 4]) = pk;
    }
    __syncthreads();
    int wv = t >> 6, lane = t & 63;
    int m = lane & 15, quad = lane >> 4;
    int p0 = blockIdx.x * 128 + wv * 32;
    float bb[8];
#pragma unroll
    for (int ot = 0; ot < 8; ot++) bb[ot] = bias[ot * 16 + m];
    floatx4 acc[2][8];
#pragma unroll
    for (int i = 0; i < 2; i++)
#pragma unroll
        for (int j = 0; j < 8; j++) acc[i][j] = (floatx4){0.f, 0.f, 0.f, 0.f};
#pragma unroll
    for (int kc = 0; kc < 4; kc++) {
        short8 a[2], b[8];
#pragma unroll
        for (int pt = 0; pt < 2; pt++)
            a[pt] = *(const short8*)(A + (size_t)(p0 + pt * 16 + m) * CH + kc * 32 + quad * 8);
#pragma unroll
        for (int ot = 0; ot < 8; ot++)
            b[ot] = *(const short8*)(&Ws[(ot * 16 + m) * 136 + kc * 32 + quad * 8]);
#pragma unroll
        for (int pt = 0; pt < 2; pt++)
#pragma unroll
            for (int ot = 0; ot < 8; ot++)
                acc[pt][ot] = __builtin_amdgcn_mfma_f32_16x16x32_bf16(a[pt], b[ot], acc[pt][ot], 0, 0, 0);
    }
#pragma unroll
    for (int pt = 0; pt < 2; pt++)
#pragma unroll
        for (int ot = 0; ot < 8; ot++)
#pragma unroll
            for (int reg = 0; reg < 4; reg++) {
                int p = p0 + pt * 16 + quad * 4 + reg;
                O[(size_t)p * CH + ot * 16 + m] = acc[pt][ot][reg] + bb[ot];
            }
}

// ---------------- attention: one wave handles head h of TWO adjacent pixels -------------
__device__ __forceinline__ int refl(int x, int n) {
    x = x < 0 ? -x : x;
    return x >= n ? 2 * (n - 1) - x : x;
}

__global__ __launch_bounds__(256) void attn_kernel(
    const float* __restrict__ q,   // [p][128] fp32
    const float* __restrict__ k,
    const float* __restrict__ v,
    unsigned short* __restrict__ att)  // [p][128] bf16
{
    int h = threadIdx.x >> 6;
    int lane = threadIdx.x & 63;
    int di = (lane >> 3) - 4;
    int dj = (lane & 7) - 4;
    int pbase = blockIdx.x * 2;

    float val[2]; int idx[2]; int ttv[2], iv[2], jv[2];
#pragma unroll
    for (int s = 0; s < 2; s++) {
        int p = pbase + s;
        int hw = p % HWS;
        int tt = p / HWS;
        int i = hw / WW, j = hw % WW;
        ttv[s] = tt; iv[s] = i; jv[s] = j;
        int pix = tt * HWS + refl(i + di, HH) * WW + refl(j + dj, WW);
        const float* qp = q + (size_t)p * CH + h * HD;
        const float* kp = k + (size_t)pix * CH + h * HD;
        float dist = 0.f;
#pragma unroll
        for (int d = 0; d < HD; d += 4) {
            float4 qv = *(const float4*)(qp + d);
            float4 kv = *(const float4*)(kp + d);
            dist += qv.x * kv.x + qv.y * kv.y + qv.z * kv.z + qv.w * kv.w;
        }
        val[s] = dist; idx[s] = lane;
    }

    // two interleaved 64-lane bitonic sorts, key = (val desc, idx asc)
#pragma unroll
    for (int kk = 2; kk <= 64; kk <<= 1) {
#pragma unroll
        for (int jj = kk >> 1; jj > 0; jj >>= 1) {
            bool dirBit = ((lane & kk) != 0) == ((lane & jj) != 0);
#pragma unroll
            for (int s = 0; s < 2; s++) {
                float o_val = __shfl_xor(val[s], jj);
                int o_idx = __shfl_xor(idx[s], jj);
                bool mineBetter = (val[s] > o_val) || (val[s] == o_val && idx[s] < o_idx);
                if (dirBit != mineBetter) { val[s] = o_val; idx[s] = o_idx; }
            }
        }
    }

    int spix[2]; float e[2], denom[2];
#pragma unroll
    for (int s = 0; s < 2; s++) {
        int sdi = (idx[s] >> 3) - 4;
        int sdj = (idx[s] & 7) - 4;
        spix[s] = ttv[s] * HWS + refl(iv[s] + sdi, HH) * WW + refl(jv[s] + sdj, WW);
        float m = __shfl(val[s], 0);
        e[s] = (lane < KTOP) ? expf(val[s] - m) : 0.f;
        denom[s] = e[s];
    }
#pragma unroll
    for (int st = 1; st < 64; st <<= 1) {
#pragma unroll
        for (int s = 0; s < 2; s++) denom[s] += __shfl_xor(denom[s], st);
    }

    const int d = lane & (HD - 1);
    float acc[2] = {0.f, 0.f};
#pragma unroll
    for (int r = 0; r < KTOP; r++) {
#pragma unroll
        for (int s = 0; s < 2; s++) {
            float ar = __shfl(e[s], r);
            int pr = __shfl(spix[s], r);
            acc[s] += ar * v[(size_t)pr * CH + h * HD + d];
        }
    }
    if (lane < HD) {
#pragma unroll
        for (int s = 0; s < 2; s++)
            att[(size_t)(pbase + s) * CH + h * HD + lane] = f2bf(acc[s] / denom[s]);
    }
}

// ---------------- proj via bf16 MFMA: out[tt][o][hw] = sum_c att[p][c] W[o][c] + b -------
__global__ __launch_bounds__(256) void proj_mfma(
    const unsigned short* __restrict__ A,   // att_bf [p][c] bf16
    const float* __restrict__ W,            // proj_w [o][c] fp32
    const float* __restrict__ bias,
    float* __restrict__ out)                // NCHW fp32
{
    __shared__ unsigned short Ws[128 * 136];
    int t = threadIdx.x;
#pragma unroll
    for (int r = 0; r < 16; r++) {
        int lin = r * 256 + t;
        int o = lin >> 5, cq = lin & 31;
        float4 w4 = *(const float4*)(W + o * CH + cq * 4);
        uint2 pk;
        pk.x = f2bf(w4.x) | ((unsigned)f2bf(w4.y) << 16);
        pk.y = f2bf(w4.z) | ((unsigned)f2bf(w4.w) << 16);
        *(uint2*)(&Ws[o * 136 + cq * 4]) = pk;
    }
    __syncthreads();
    int wv = t >> 6, lane = t & 63;
    int m = lane & 15, quad = lane >> 4;
    int p0 = blockIdx.x * 128;
    int o0 = wv * 32;
    float bb[2][4];
#pragma unroll
    for (int ot = 0; ot < 2; ot++)
#pragma unroll
        for (int reg = 0; reg < 4; reg++) bb[ot][reg] = bias[o0 + ot * 16 + quad * 4 + reg];
    floatx4 acc[2][8];
#pragma unroll
    for (int i = 0; i < 2; i++)
#pragma unroll
        for (int j = 0; j < 8; j++) acc[i][j] = (floatx4){0.f, 0.f, 0.f, 0.f};
#pragma unroll
    for (int kc = 0; kc < 4; kc++) {
        short8 a[2], b[8];
#pragma unroll
        for (int ot = 0; ot < 2; ot++)
            a[ot] = *(const short8*)(&Ws[(o0 + ot * 16 + m) * 136 + kc * 32 + quad * 8]);
#pragma unroll
        for (int pt = 0; pt < 8; pt++)
            b[pt] = *(const short8*)(A + (size_t)(p0 + pt * 16 + m) * CH + kc * 32 + quad * 8);
#pragma unroll
        for (int ot = 0; ot < 2; ot++)
#pragma unroll
            for (int pt = 0; pt < 8; pt++)
                acc[ot][pt] = __builtin_amdgcn_mfma_f32_16x16x32_bf16(a[ot], b[pt], acc[ot][pt], 0, 0, 0);
    }
    int tt = p0 / HWS;
    int hwb = p0 - tt * HWS;
#pragma unroll
    for (int ot = 0; ot < 2; ot++)
#pragma unroll
        for (int pt = 0; pt < 8; pt++)
#pragma unroll
            for (int reg = 0; reg < 4; reg++) {
                int o = o0 + ot * 16 + quad * 4 + reg;
                int hw = hwb + pt * 16 + m;
                out[((size_t)(tt * CH + o)) * HWS + hw] = acc[ot][pt][reg] + bb[ot][reg];
            }
}

extern "C" void kernel_launch(void* const* d_in, const int* in_sizes, int n_in,
                              void* d_out, int out_size, void* d_ws, size_t ws_size,
                              hipStream_t stream) {
    const float* vid    = (const float*)d_in[0];
    const float* wq_dw  = (const float*)d_in[1];
    const float* wq_pw  = (const float*)d_in[2];
    const float* bq     = (const float*)d_in[3];
    const float* wk_dw  = (const float*)d_in[4];
    const float* wk_pw  = (const float*)d_in[5];
    const float* bk     = (const float*)d_in[6];
    const float* wv_dw  = (const float*)d_in[7];
    const float* wv_pw  = (const float*)d_in[8];
    const float* bv     = (const float*)d_in[9];
    const float* proj_w = (const float*)d_in[10];
    const float* proj_b = (const float*)d_in[11];
    float* out = (float*)d_out;

    float* t_dw = (float*)d_ws;                       // 3*QC fp32  [sel][c][p]
    float* qkv  = t_dw + (size_t)3 * QC;              // 3*QC fp32  [p][c] q,k,v
    unsigned short* v_bf = (unsigned short*)(qkv + (size_t)3 * QC);  // QC bf16 [p][c]
    unsigned short* att_bf = v_bf;                    // alias: reused after vgemm

    dw_kernel<<<dim3(QTOT * CH / 256, 3), 256, 0, stream>>>(vid, wq_dw, wk_dw, wv_dw, t_dw);
    transcvt_v<<<dim3(QTOT / 64, 4), 256, 0, stream>>>(t_dw + (size_t)2 * QC, v_bf);
    gemm_qk_kernel<<<dim3(QTOT / 64, 2), 256, 0, stream>>>(t_dw, wq_pw, bq, wk_pw, bk, qkv);
    vgemm_mfma<<<QTOT / 128, 256, 0, stream>>>(v_bf, wv_pw, bv, qkv + (size_t)2 * QC);
    attn_kernel<<<QTOT / 2, 256, 0, stream>>>(qkv, qkv + QC, qkv + (size_t)2 * QC, att_bf);
    proj_mfma<<<QTOT / 128, 256, 0, stream>>>(att_bf, proj_w, proj_b, out);
}

// Round 3
// 264.700 us; speedup vs baseline: 1.1641x; 1.0599x over previous
//
#include <hip/hip_runtime.h>
#include <math.h>

#define TT 2
#define CH 128
#define HH 96
#define WW 96
#define HWS 9216            // H*W
#define QTOT 18432          // T*H*W
#define QC (QTOT*CH)
#define HD 32
#define KTOP 16
#define SCALE 0.17677669529663687f  // 32^-0.5

typedef __attribute__((ext_vector_type(8))) short short8;
typedef __attribute__((ext_vector_type(4))) float floatx4;

__device__ __forceinline__ unsigned short f2bf(float f) {
    union { float f; unsigned u; } x; x.f = f;
    unsigned r = x.u + 0x7fffu + ((x.u >> 16) & 1u);
    return (unsigned short)(r >> 16);
}

// ---------------- depthwise 3x3 (zero-pad SAME), out fp32 [sel][c][p] ----------------
__global__ __launch_bounds__(256) void dw_kernel(
    const float* __restrict__ x,
    const float* __restrict__ wq, const float* __restrict__ wk, const float* __restrict__ wv,
    float* __restrict__ t_dw)
{
    int sel = blockIdx.y;
    const float* wdw = sel == 0 ? wq : (sel == 1 ? wk : wv);
    int tid = blockIdx.x * 256 + threadIdx.x;
    int hw = tid % HWS;
    int cf = tid / HWS;
    int c = cf & (CH - 1);
    int tt = cf >> 7;
    int i = hw / WW, j = hw % WW;
    const float* xp = x + (size_t)(tt * CH + c) * HWS;
    float w[9];
#pragma unroll
    for (int r = 0; r < 9; r++) w[r] = wdw[c * 9 + r];
    float s = 0.f;
#pragma unroll
    for (int r = 0; r < 3; r++) {
        int ii = i + r - 1;
        if (ii < 0 || ii >= HH) continue;
#pragma unroll
        for (int ss = 0; ss < 3; ss++) {
            int jj = j + ss - 1;
            if (jj < 0 || jj >= WW) continue;
            s += xp[ii * WW + jj] * w[r * 3 + ss];
        }
    }
    t_dw[(size_t)sel * QC + (size_t)c * QTOT + tt * HWS + hw] = s;
}

// ---------------- transpose+convert v: [c][p] fp32 -> [p][c] bf16 ----------------
__global__ __launch_bounds__(256) void transcvt_v(
    const float* __restrict__ vd, unsigned short* __restrict__ vb)
{
    __shared__ float s[64][33];
    int t = threadIdx.x;
    int p0 = blockIdx.x * 64;
    int c0 = blockIdx.y * 32;
#pragma unroll
    for (int r = 0; r < 2; r++) {
        int lin = r * 256 + t;
        int c = lin >> 4;
        int pq = lin & 15;
        float4 v4 = *(const float4*)(vd + (size_t)(c0 + c) * QTOT + p0 + pq * 4);
        s[pq * 4 + 0][c] = v4.x; s[pq * 4 + 1][c] = v4.y;
        s[pq * 4 + 2][c] = v4.z; s[pq * 4 + 3][c] = v4.w;
    }
    __syncthreads();
    int p = t >> 2, cq = t & 3;
    unsigned u[8];
#pragma unroll
    for (int j = 0; j < 8; j++) u[j] = f2bf(s[p][cq * 8 + j]);
    uint4 pack;
    pack.x = u[0] | (u[1] << 16); pack.y = u[2] | (u[3] << 16);
    pack.z = u[4] | (u[5] << 16); pack.w = u[6] | (u[7] << 16);
    *(uint4*)(vb + (size_t)(p0 + p) * CH + c0 + cq * 8) = pack;
}

// ---------------- fp32 pointwise GEMM for q,k (64px x 64o tiles, fp32-exact) ----------
__global__ __launch_bounds__(256) void gemm_qk_kernel(
    const float* __restrict__ t_dw,
    const float* __restrict__ wq_pw, const float* __restrict__ bq,
    const float* __restrict__ wk_pw, const float* __restrict__ bk,
    float* __restrict__ out)
{
    int sel = blockIdx.y >> 1;       // 0=q, 1=k
    int o0 = (blockIdx.y & 1) * 64;
    const float* Wg = sel == 0 ? wq_pw : wk_pw;
    const float* bg = sel == 0 ? bq : bk;
    const float* A = t_dw + (size_t)sel * QC;   // [c][p]
    float* O = out + (size_t)sel * QC;          // [p][c]
    float scale = sel == 0 ? SCALE : 1.f;

    __shared__ float A_s[32][64];
    __shared__ float Wt_s[32][68];   // [cc][oo]; stride 68: 16B-aligned rows, 2-way-max banks
    int tid = threadIdx.x;
    int o_grp = tid & 15;            // 4 o's each
    int p_grp = tid >> 4;            // 4 p's each
    int pbase = blockIdx.x * 64;
    float acc[4][4] = {};

    for (int c0 = 0; c0 < CH; c0 += 32) {
#pragma unroll
        for (int r = 0; r < 8; r++) {
            int lin = r * 256 + tid;
            int cc = lin >> 6, pp = lin & 63;
            A_s[cc][pp] = A[(size_t)(c0 + cc) * QTOT + pbase + pp];
        }
#pragma unroll
        for (int r = 0; r < 8; r++) {
            int lin = r * 256 + tid;
            int cc = lin & 31, oo = lin >> 5;
            Wt_s[cc][oo] = Wg[(o0 + oo) * CH + c0 + cc];
        }
        __syncthreads();
#pragma unroll 8
        for (int cc = 0; cc < 32; cc++) {
            float4 a4 = *(const float4*)&A_s[cc][p_grp * 4];
            float4 b4 = *(const float4*)&Wt_s[cc][o_grp * 4];
            float a[4] = {a4.x, a4.y, a4.z, a4.w};
            float b[4] = {b4.x, b4.y, b4.z, b4.w};
#pragma unroll
            for (int i = 0; i < 4; i++)
#pragma unroll
                for (int k = 0; k < 4; k++) acc[i][k] += a[i] * b[k];
        }
        __syncthreads();
    }
    float bb[4];
#pragma unroll
    for (int k = 0; k < 4; k++) bb[k] = bg[o0 + o_grp * 4 + k];
#pragma unroll
    for (int i = 0; i < 4; i++) {
        int p = pbase + p_grp * 4 + i;
        float4 st;
        st.x = (acc[i][0] + bb[0]) * scale;
        st.y = (acc[i][1] + bb[1]) * scale;
        st.z = (acc[i][2] + bb[2]) * scale;
        st.w = (acc[i][3] + bb[3]) * scale;
        *(float4*)&O[(size_t)p * CH + o0 + o_grp * 4] = st;
    }
}

// ---------------- v pointwise via bf16 MFMA (64-px blocks) ----------------
__global__ __launch_bounds__(256) void vgemm_mfma(
    const unsigned short* __restrict__ A,   // v_bf [p][c] bf16
    const float* __restrict__ W,            // [o][c] fp32
    const float* __restrict__ bias,
    float* __restrict__ O)                  // fp32 [p][c]
{
    __shared__ unsigned short Ws[128 * 136];
    int t = threadIdx.x;
#pragma unroll
    for (int r = 0; r < 16; r++) {
        int lin = r * 256 + t;
        int o = lin >> 5, cq = lin & 31;
        float4 w4 = *(const float4*)(W + o * CH + cq * 4);
        uint2 pk;
        pk.x = f2bf(w4.x) | ((unsigned)f2bf(w4.y) << 16);
        pk.y = f2bf(w4.z) | ((unsigned)f2bf(w4.w) << 16);
        *(uint2*)(&Ws[o * 136 + cq * 4]) = pk;
    }
    __syncthreads();
    int wv = t >> 6, lane = t & 63;
    int m = lane & 15, quad = lane >> 4;
    int p0 = blockIdx.x * 64;
    int o0 = wv * 32;
    float bb[2];
#pragma unroll
    for (int ot = 0; ot < 2; ot++) bb[ot] = bias[o0 + ot * 16 + m];
    floatx4 acc[4][2];
#pragma unroll
    for (int i = 0; i < 4; i++)
#pragma unroll
        for (int j = 0; j < 2; j++) acc[i][j] = (floatx4){0.f, 0.f, 0.f, 0.f};
#pragma unroll
    for (int kc = 0; kc < 4; kc++) {
        short8 a[4], b[2];
#pragma unroll
        for (int pt = 0; pt < 4; pt++)
            a[pt] = *(const short8*)(A + (size_t)(p0 + pt * 16 + m) * CH + kc * 32 + quad * 8);
#pragma unroll
        for (int ot = 0; ot < 2; ot++)
            b[ot] = *(const short8*)(&Ws[(o0 + ot * 16 + m) * 136 + kc * 32 + quad * 8]);
#pragma unroll
        for (int pt = 0; pt < 4; pt++)
#pragma unroll
            for (int ot = 0; ot < 2; ot++)
                acc[pt][ot] = __builtin_amdgcn_mfma_f32_16x16x32_bf16(a[pt], b[ot], acc[pt][ot], 0, 0, 0);
    }
#pragma unroll
    for (int pt = 0; pt < 4; pt++)
#pragma unroll
        for (int ot = 0; ot < 2; ot++)
#pragma unroll
            for (int reg = 0; reg < 4; reg++) {
                int p = p0 + pt * 16 + quad * 4 + reg;
                O[(size_t)p * CH + o0 + ot * 16 + m] = acc[pt][ot][reg] + bb[ot];
            }
}

// ---------------- attention: radix-select top-16, zero LDS-pipe cross-lane ------------
__device__ __forceinline__ int refl(int x, int n) {
    x = x < 0 ? -x : x;
    return x >= n ? 2 * (n - 1) - x : x;
}

__global__ __launch_bounds__(256) void attn_kernel(
    const float* __restrict__ q,   // [p][128] fp32
    const float* __restrict__ k,
    const float* __restrict__ v,
    unsigned short* __restrict__ att)  // [p][128] bf16
{
    int h = threadIdx.x >> 6;
    int lane = threadIdx.x & 63;
    int di = (lane >> 3) - 4;
    int dj = (lane & 7) - 4;
    int pbase = blockIdx.x * 2;

    float val[2]; int cpix[2];
#pragma unroll
    for (int s = 0; s < 2; s++) {
        int p = pbase + s;
        int hw = p % HWS;
        int tt = p / HWS;
        int i = hw / WW, j = hw % WW;
        int pix = tt * HWS + refl(i + di, HH) * WW + refl(j + dj, WW);
        cpix[s] = pix;
        const float* qp = q + (size_t)p * CH + h * HD;
        const float* kp = k + (size_t)pix * CH + h * HD;
        float dist = 0.f;
#pragma unroll
        for (int d = 0; d < HD; d += 4) {
            float4 qv = *(const float4*)(qp + d);
            float4 kv = *(const float4*)(kp + d);
            dist += qv.x * kv.x + qv.y * kv.y + qv.z * kv.z + qv.w * kv.w;
        }
        val[s] = dist;
    }

    // order-preserving uint key (desc select): neg -> ~u, pos -> u|signbit
    unsigned key[2];
#pragma unroll
    for (int s = 0; s < 2; s++) {
        unsigned u = __float_as_uint(val[s]);
        key[s] = (u & 0x80000000u) ? ~u : (u | 0x80000000u);
    }

    // radix-select the 16th-largest key (exact, bitwise)
    unsigned prefix[2] = {0u, 0u};
    int need[2] = {KTOP, KTOP};
#pragma unroll
    for (int bit = 31; bit >= 0; --bit) {
#pragma unroll
        for (int s = 0; s < 2; s++) {
            unsigned hi = (prefix[s] >> bit) | 1u;
            unsigned long long b = __ballot((key[s] >> bit) == hi);
            int cnt = __popcll(b);
            bool take = cnt >= need[s];
            prefix[s] = take ? (prefix[s] | (1u << bit)) : prefix[s];
            need[s] = take ? need[s] : need[s] - cnt;
        }
    }

    // selection set: key > kth, plus first `need` of the tie class by lane asc
    unsigned long long selm[2]; float e[2];
#pragma unroll
    for (int s = 0; s < 2; s++) {
        bool isEq = (key[s] == prefix[s]);
        unsigned long long eqm = __ballot(isEq);
        unsigned long long below = (1ull << lane) - 1ull;
        int rk = __popcll(eqm & below);
        bool sel = (key[s] > prefix[s]) || (isEq && rk < need[s]);
        selm[s] = __ballot(sel);
        unsigned up = (prefix[s] & 0x80000000u) ? (prefix[s] & 0x7fffffffu) : ~prefix[s];
        float vth = __uint_as_float(up);
        e[s] = sel ? __expf(val[s] - vth) : 0.f;   // uniform shift == softmax-invariant
    }

    // walk the 16 selected lanes: scalar ctz + v_readlane (no LDS pipe)
    const int d = lane & (HD - 1);
    float acc[2] = {0.f, 0.f}, denom[2] = {0.f, 0.f};
    unsigned long long m0 = selm[0], m1 = selm[1];
#pragma unroll
    for (int r = 0; r < KTOP; r++) {
        int s0 = __builtin_ctzll(m0); m0 &= m0 - 1ull;
        int s1 = __builtin_ctzll(m1); m1 &= m1 - 1ull;
        float a0 = __uint_as_float((unsigned)__builtin_amdgcn_readlane((int)__float_as_uint(e[0]), s0));
        float a1 = __uint_as_float((unsigned)__builtin_amdgcn_readlane((int)__float_as_uint(e[1]), s1));
        int p0 = __builtin_amdgcn_readlane(cpix[0], s0);
        int p1 = __builtin_amdgcn_readlane(cpix[1], s1);
        denom[0] += a0; denom[1] += a1;
        acc[0] += a0 * v[(size_t)p0 * CH + h * HD + d];
        acc[1] += a1 * v[(size_t)p1 * CH + h * HD + d];
    }
    if (lane < HD) {
        att[(size_t)(pbase + 0) * CH + h * HD + lane] = f2bf(acc[0] / denom[0]);
        att[(size_t)(pbase + 1) * CH + h * HD + lane] = f2bf(acc[1] / denom[1]);
    }
}

// ---------------- proj via bf16 MFMA (64-px blocks) ----------------
__global__ __launch_bounds__(256) void proj_mfma(
    const unsigned short* __restrict__ A,   // att_bf [p][c] bf16
    const float* __restrict__ W,            // proj_w [o][c] fp32
    const float* __restrict__ bias,
    float* __restrict__ out)                // NCHW fp32
{
    __shared__ unsigned short Ws[128 * 136];
    int t = threadIdx.x;
#pragma unroll
    for (int r = 0; r < 16; r++) {
        int lin = r * 256 + t;
        int o = lin >> 5, cq = lin & 31;
        float4 w4 = *(const float4*)(W + o * CH + cq * 4);
        uint2 pk;
        pk.x = f2bf(w4.x) | ((unsigned)f2bf(w4.y) << 16);
        pk.y = f2bf(w4.z) | ((unsigned)f2bf(w4.w) << 16);
        *(uint2*)(&Ws[o * 136 + cq * 4]) = pk;
    }
    __syncthreads();
    int wv = t >> 6, lane = t & 63;
    int m = lane & 15, quad = lane >> 4;
    int p0 = blockIdx.x * 64;
    int o0 = wv * 32;
    float bb[2][4];
#pragma unroll
    for (int ot = 0; ot < 2; ot++)
#pragma unroll
        for (int reg = 0; reg < 4; reg++) bb[ot][reg] = bias[o0 + ot * 16 + quad * 4 + reg];
    floatx4 acc[2][4];
#pragma unroll
    for (int i = 0; i < 2; i++)
#pragma unroll
        for (int j = 0; j < 4; j++) acc[i][j] = (floatx4){0.f, 0.f, 0.f, 0.f};
#pragma unroll
    for (int kc = 0; kc < 4; kc++) {
        short8 a[2], b[4];
#pragma unroll
        for (int ot = 0; ot < 2; ot++)
            a[ot] = *(const short8*)(&Ws[(o0 + ot * 16 + m) * 136 + kc * 32 + quad * 8]);
#pragma unroll
        for (int pt = 0; pt < 4; pt++)
            b[pt] = *(const short8*)(A + (size_t)(p0 + pt * 16 + m) * CH + kc * 32 + quad * 8);
#pragma unroll
        for (int ot = 0; ot < 2; ot++)
#pragma unroll
            for (int pt = 0; pt < 4; pt++)
                acc[ot][pt] = __builtin_amdgcn_mfma_f32_16x16x32_bf16(a[ot], b[pt], acc[ot][pt], 0, 0, 0);
    }
    int tt = p0 / HWS;
    int hwb = p0 - tt * HWS;
#pragma unroll
    for (int ot = 0; ot < 2; ot++)
#pragma unroll
        for (int pt = 0; pt < 4; pt++)
#pragma unroll
            for (int reg = 0; reg < 4; reg++) {
                int o = o0 + ot * 16 + quad * 4 + reg;
                int hw = hwb + pt * 16 + m;
                out[((size_t)(tt * CH + o)) * HWS + hw] = acc[ot][pt][reg] + bb[ot][reg];
            }
}

extern "C" void kernel_launch(void* const* d_in, const int* in_sizes, int n_in,
                              void* d_out, int out_size, void* d_ws, size_t ws_size,
                              hipStream_t stream) {
    const float* vid    = (const float*)d_in[0];
    const float* wq_dw  = (const float*)d_in[1];
    const float* wq_pw  = (const float*)d_in[2];
    const float* bq     = (const float*)d_in[3];
    const float* wk_dw  = (const float*)d_in[4];
    const float* wk_pw  = (const float*)d_in[5];
    const float* bk     = (const float*)d_in[6];
    const float* wv_dw  = (const float*)d_in[7];
    const float* wv_pw  = (const float*)d_in[8];
    const float* bv     = (const float*)d_in[9];
    const float* proj_w = (const float*)d_in[10];
    const float* proj_b = (const float*)d_in[11];
    float* out = (float*)d_out;

    float* t_dw = (float*)d_ws;                       // 3*QC fp32  [sel][c][p]
    float* qkv  = t_dw + (size_t)3 * QC;              // 3*QC fp32  [p][c] q,k,v
    unsigned short* v_bf = (unsigned short*)(qkv + (size_t)3 * QC);  // QC bf16
    unsigned short* att_bf = v_bf;                    // alias: reused after vgemm

    dw_kernel<<<dim3(QTOT * CH / 256, 3), 256, 0, stream>>>(vid, wq_dw, wk_dw, wv_dw, t_dw);
    transcvt_v<<<dim3(QTOT / 64, 4), 256, 0, stream>>>(t_dw + (size_t)2 * QC, v_bf);
    gemm_qk_kernel<<<dim3(QTOT / 64, 4), 256, 0, stream>>>(t_dw, wq_pw, bq, wk_pw, bk, qkv);
    vgemm_mfma<<<QTOT / 64, 256, 0, stream>>>(v_bf, wv_pw, bv, qkv + (size_t)2 * QC);
    attn_kernel<<<QTOT / 2, 256, 0, stream>>>(qkv, qkv + QC, qkv + (size_t)2 * QC, att_bf);
    proj_mfma<<<QTOT / 64, 256, 0, stream>>>(att_bf, proj_w, proj_b, out);
}

// Round 4
// 217.523 us; speedup vs baseline: 1.4166x; 1.2169x over previous
//
#include <hip/hip_runtime.h>
#include <math.h>

#define TT 2
#define CH 128
#define HH 96
#define WW 96
#define HWS 9216            // H*W
#define QTOT 18432          // T*H*W
#define QC (QTOT*CH)
#define HD 32
#define KTOP 16
#define SCALE 0.17677669529663687f  // 32^-0.5

#define SEG 16              // queries per attn block (one row segment)
#define PR 8                // patch rows
#define PC 23               // patch cols
#define PSTRIDE 36          // floats per patch pixel in LDS (16B-aligned, bank-spread)

typedef __attribute__((ext_vector_type(8))) short short8;
typedef __attribute__((ext_vector_type(4))) float floatx4;

__device__ __forceinline__ unsigned short f2bf(float f) {
    union { float f; unsigned u; } x; x.f = f;
    unsigned r = x.u + 0x7fffu + ((x.u >> 16) & 1u);
    return (unsigned short)(r >> 16);
}

__device__ __forceinline__ int refl(int x, int n) {
    x = x < 0 ? -x : x;
    return x >= n ? 2 * (n - 1) - x : x;
}

// ---------------- depthwise 3x3 (zero-pad SAME), out fp32 [sel][c][p] ----------------
__global__ __launch_bounds__(256) void dw_kernel(
    const float* __restrict__ x,
    const float* __restrict__ wq, const float* __restrict__ wk, const float* __restrict__ wv,
    float* __restrict__ t_dw)
{
    int sel = blockIdx.y;
    const float* wdw = sel == 0 ? wq : (sel == 1 ? wk : wv);
    int tid = blockIdx.x * 256 + threadIdx.x;
    int hw = tid % HWS;
    int cf = tid / HWS;
    int c = cf & (CH - 1);
    int tt = cf >> 7;
    int i = hw / WW, j = hw % WW;
    const float* xp = x + (size_t)(tt * CH + c) * HWS;
    float w[9];
#pragma unroll
    for (int r = 0; r < 9; r++) w[r] = wdw[c * 9 + r];
    float s = 0.f;
#pragma unroll
    for (int r = 0; r < 3; r++) {
        int ii = i + r - 1;
        if (ii < 0 || ii >= HH) continue;
#pragma unroll
        for (int ss = 0; ss < 3; ss++) {
            int jj = j + ss - 1;
            if (jj < 0 || jj >= WW) continue;
            s += xp[ii * WW + jj] * w[r * 3 + ss];
        }
    }
    t_dw[(size_t)sel * QC + (size_t)c * QTOT + tt * HWS + hw] = s;
}

// ---------------- transpose+convert v: [c][p] fp32 -> [p][c] bf16 ----------------
__global__ __launch_bounds__(256) void transcvt_v(
    const float* __restrict__ vd, unsigned short* __restrict__ vb)
{
    __shared__ float s[64][33];
    int t = threadIdx.x;
    int p0 = blockIdx.x * 64;
    int c0 = blockIdx.y * 32;
#pragma unroll
    for (int r = 0; r < 2; r++) {
        int lin = r * 256 + t;
        int c = lin >> 4;
        int pq = lin & 15;
        float4 v4 = *(const float4*)(vd + (size_t)(c0 + c) * QTOT + p0 + pq * 4);
        s[pq * 4 + 0][c] = v4.x; s[pq * 4 + 1][c] = v4.y;
        s[pq * 4 + 2][c] = v4.z; s[pq * 4 + 3][c] = v4.w;
    }
    __syncthreads();
    int p = t >> 2, cq = t & 3;
    unsigned u[8];
#pragma unroll
    for (int j = 0; j < 8; j++) u[j] = f2bf(s[p][cq * 8 + j]);
    uint4 pack;
    pack.x = u[0] | (u[1] << 16); pack.y = u[2] | (u[3] << 16);
    pack.z = u[4] | (u[5] << 16); pack.w = u[6] | (u[7] << 16);
    *(uint4*)(vb + (size_t)(p0 + p) * CH + c0 + cq * 8) = pack;
}

// ---------------- fp32 pointwise GEMM for q,k: 128px x 64o tiles, 8x4/thread ----------
__global__ __launch_bounds__(256) void gemm_qk_kernel(
    const float* __restrict__ t_dw,
    const float* __restrict__ wq_pw, const float* __restrict__ bq,
    const float* __restrict__ wk_pw, const float* __restrict__ bk,
    float* __restrict__ out)
{
    int sel = blockIdx.y >> 1;       // 0=q, 1=k
    int o0 = (blockIdx.y & 1) * 64;
    const float* Wg = sel == 0 ? wq_pw : wk_pw;
    const float* bg = sel == 0 ? bq : bk;
    const float* A = t_dw + (size_t)sel * QC;   // [c][p]
    float* O = out + (size_t)sel * QC;          // [p][c]
    float scale = sel == 0 ? SCALE : 1.f;

    __shared__ float A_s[32][128];
    __shared__ float Wt_s[32][68];   // [cc][oo]; 68 = 17 granules: aligned + spread
    int tid = threadIdx.x;
    int o_grp = tid & 15;            // 4 o's
    int p_grp = tid >> 4;            // 8 p's
    int pbase = blockIdx.x * 128;
    float acc[8][4] = {};

    for (int c0 = 0; c0 < CH; c0 += 32) {
#pragma unroll
        for (int r = 0; r < 4; r++) {
            int lin = r * 256 + tid;
            int cc = lin >> 5, pq = lin & 31;
            *(float4*)&A_s[cc][pq * 4] =
                *(const float4*)&A[(size_t)(c0 + cc) * QTOT + pbase + pq * 4];
        }
#pragma unroll
        for (int r = 0; r < 2; r++) {
            int f = r * 256 + tid;
            int oo = f & 63, c4 = f >> 6;    // c4: 0..7
            float4 w4 = *(const float4*)&Wg[(o0 + oo) * CH + c0 + c4 * 4];
            Wt_s[c4 * 4 + 0][oo] = w4.x;
            Wt_s[c4 * 4 + 1][oo] = w4.y;
            Wt_s[c4 * 4 + 2][oo] = w4.z;
            Wt_s[c4 * 4 + 3][oo] = w4.w;
        }
        __syncthreads();
#pragma unroll 8
        for (int cc = 0; cc < 32; cc++) {
            float4 a0 = *(const float4*)&A_s[cc][p_grp * 8];
            float4 a1 = *(const float4*)&A_s[cc][p_grp * 8 + 4];
            float4 b4 = *(const float4*)&Wt_s[cc][o_grp * 4];
            float a[8] = {a0.x, a0.y, a0.z, a0.w, a1.x, a1.y, a1.z, a1.w};
            float b[4] = {b4.x, b4.y, b4.z, b4.w};
#pragma unroll
            for (int i = 0; i < 8; i++)
#pragma unroll
                for (int kq = 0; kq < 4; kq++) acc[i][kq] += a[i] * b[kq];
        }
        __syncthreads();
    }
    float bb[4];
#pragma unroll
    for (int kq = 0; kq < 4; kq++) bb[kq] = bg[o0 + o_grp * 4 + kq];
#pragma unroll
    for (int i = 0; i < 8; i++) {
        int p = pbase + p_grp * 8 + i;
        float4 st;
        st.x = (acc[i][0] + bb[0]) * scale;
        st.y = (acc[i][1] + bb[1]) * scale;
        st.z = (acc[i][2] + bb[2]) * scale;
        st.w = (acc[i][3] + bb[3]) * scale;
        *(float4*)&O[(size_t)p * CH + o0 + o_grp * 4] = st;
    }
}

// ---------------- v pointwise via bf16 MFMA (64-px blocks) ----------------
__global__ __launch_bounds__(256) void vgemm_mfma(
    const unsigned short* __restrict__ A,   // v_bf [p][c] bf16
    const float* __restrict__ W,            // [o][c] fp32
    const float* __restrict__ bias,
    float* __restrict__ O)                  // fp32 [p][c]
{
    __shared__ unsigned short Ws[128 * 136];
    int t = threadIdx.x;
#pragma unroll
    for (int r = 0; r < 16; r++) {
        int lin = r * 256 + t;
        int o = lin >> 5, cq = lin & 31;
        float4 w4 = *(const float4*)(W + o * CH + cq * 4);
        uint2 pk;
        pk.x = f2bf(w4.x) | ((unsigned)f2bf(w4.y) << 16);
        pk.y = f2bf(w4.z) | ((unsigned)f2bf(w4.w) << 16);
        *(uint2*)(&Ws[o * 136 + cq * 4]) = pk;
    }
    __syncthreads();
    int wv = t >> 6, lane = t & 63;
    int m = lane & 15, quad = lane >> 4;
    int p0 = blockIdx.x * 64;
    int o0 = wv * 32;
    float bb[2];
#pragma unroll
    for (int ot = 0; ot < 2; ot++) bb[ot] = bias[o0 + ot * 16 + m];
    floatx4 acc[4][2];
#pragma unroll
    for (int i = 0; i < 4; i++)
#pragma unroll
        for (int j = 0; j < 2; j++) acc[i][j] = (floatx4){0.f, 0.f, 0.f, 0.f};
#pragma unroll
    for (int kc = 0; kc < 4; kc++) {
        short8 a[4], b[2];
#pragma unroll
        for (int pt = 0; pt < 4; pt++)
            a[pt] = *(const short8*)(A + (size_t)(p0 + pt * 16 + m) * CH + kc * 32 + quad * 8);
#pragma unroll
        for (int ot = 0; ot < 2; ot++)
            b[ot] = *(const short8*)(&Ws[(o0 + ot * 16 + m) * 136 + kc * 32 + quad * 8]);
#pragma unroll
        for (int pt = 0; pt < 4; pt++)
#pragma unroll
            for (int ot = 0; ot < 2; ot++)
                acc[pt][ot] = __builtin_amdgcn_mfma_f32_16x16x32_bf16(a[pt], b[ot], acc[pt][ot], 0, 0, 0);
    }
#pragma unroll
    for (int pt = 0; pt < 4; pt++)
#pragma unroll
        for (int ot = 0; ot < 2; ot++)
#pragma unroll
            for (int reg = 0; reg < 4; reg++) {
                int p = p0 + pt * 16 + quad * 4 + reg;
                O[(size_t)p * CH + o0 + ot * 16 + m] = acc[pt][ot][reg] + bb[ot];
            }
}

// ---------------- attention: LDS k-patch per 16-query row segment ----------------
__global__ __launch_bounds__(256) void attn_kernel(
    const float* __restrict__ q,   // [p][128] fp32
    const float* __restrict__ k,
    const float* __restrict__ v,
    unsigned short* __restrict__ att)  // [p][128] bf16
{
    __shared__ float kp[PR * PC * PSTRIDE];   // 26.5 KB
    int h = blockIdx.y;
    int seg = blockIdx.x;
    int qj0 = (seg % (WW / SEG)) * SEG;
    int qi = (seg / (WW / SEG)) % HH;
    int tt = seg / ((WW / SEG) * HH);
    int t = threadIdx.x;

    // stage reflected k patch: coalesced (8 lines/inst instead of 64)
#pragma unroll
    for (int r = 0; r < 6; r++) {
        int f = r * 256 + t;
        if (f < PR * PC * 8) {
            int pix = f >> 3, d4 = f & 7;
            int ci = pix / PC, cj = pix - ci * PC;
            int gi = refl(qi + ci - 4, HH);
            int gj = refl(qj0 + cj - 4, WW);
            int gp = tt * HWS + gi * WW + gj;
            *(float4*)(&kp[pix * PSTRIDE + d4 * 4]) =
                *(const float4*)(k + (size_t)gp * CH + h * HD + d4 * 4);
        }
    }
    __syncthreads();

    int wv = t >> 6, lane = t & 63;
    int ci = lane >> 3, cjo = lane & 7;
    int di = ci - 4, dj = cjo - 4;
    int rowoff = tt * HWS + refl(qi + di, HH) * WW;
    const int d = lane & (HD - 1);

    for (int ql = wv * 4; ql < wv * 4 + 4; ql++) {
        int qj = qj0 + ql;
        int p = tt * HWS + qi * WW + qj;
        const float* qp = q + (size_t)p * CH + h * HD;
        const float* kr = &kp[(ci * PC + ql + cjo) * PSTRIDE];
        float dist = 0.f;
#pragma unroll
        for (int dd = 0; dd < 8; dd++) {
            float4 qv = *(const float4*)(qp + dd * 4);
            float4 kv = *(const float4*)(kr + dd * 4);
            dist += qv.x * kv.x + qv.y * kv.y + qv.z * kv.z + qv.w * kv.w;
        }
        int cpix = rowoff + refl(qj + dj, WW);

        // order-preserving uint key (desc select)
        unsigned u = __float_as_uint(dist);
        unsigned key = (u & 0x80000000u) ? ~u : (u | 0x80000000u);

        // radix-select the 16th-largest key (exact, bitwise)
        unsigned prefix = 0u;
        int need = KTOP;
#pragma unroll
        for (int bit = 31; bit >= 0; --bit) {
            unsigned hi = (prefix >> bit) | 1u;
            unsigned long long b = __ballot((key >> bit) == hi);
            int cnt = __popcll(b);
            bool take = cnt >= need;
            prefix = take ? (prefix | (1u << bit)) : prefix;
            need = take ? need : need - cnt;
        }

        // selection set: key > kth, plus first `need` of tie class by lane asc
        bool isEq = (key == prefix);
        unsigned long long eqm = __ballot(isEq);
        unsigned long long below = (1ull << lane) - 1ull;
        int rk = __popcll(eqm & below);
        bool selb = (key > prefix) || (isEq && rk < need);
        unsigned long long selm = __ballot(selb);
        unsigned up = (prefix & 0x80000000u) ? (prefix & 0x7fffffffu) : ~prefix;
        float vth = __uint_as_float(up);
        float e = selb ? __expf(dist - vth) : 0.f;

        // walk 16 selected lanes: scalar ctz + readlane, broadcast v rows
        float acc = 0.f, denom = 0.f;
        unsigned long long m0 = selm;
#pragma unroll
        for (int r = 0; r < KTOP; r++) {
            int s0 = __builtin_ctzll(m0); m0 &= m0 - 1ull;
            float a0 = __uint_as_float((unsigned)__builtin_amdgcn_readlane((int)__float_as_uint(e), s0));
            int p0 = __builtin_amdgcn_readlane(cpix, s0);
            denom += a0;
            acc += a0 * v[(size_t)p0 * CH + h * HD + d];
        }
        if (lane < HD)
            att[(size_t)p * CH + h * HD + lane] = f2bf(acc / denom);
    }
}

// ---------------- proj via bf16 MFMA (64-px blocks) ----------------
__global__ __launch_bounds__(256) void proj_mfma(
    const unsigned short* __restrict__ A,   // att_bf [p][c] bf16
    const float* __restrict__ W,            // proj_w [o][c] fp32
    const float* __restrict__ bias,
    float* __restrict__ out)                // NCHW fp32
{
    __shared__ unsigned short Ws[128 * 136];
    int t = threadIdx.x;
#pragma unroll
    for (int r = 0; r < 16; r++) {
        int lin = r * 256 + t;
        int o = lin >> 5, cq = lin & 31;
        float4 w4 = *(const float4*)(W + o * CH + cq * 4);
        uint2 pk;
        pk.x = f2bf(w4.x) | ((unsigned)f2bf(w4.y) << 16);
        pk.y = f2bf(w4.z) | ((unsigned)f2bf(w4.w) << 16);
        *(uint2*)(&Ws[o * 136 + cq * 4]) = pk;
    }
    __syncthreads();
    int wv = t >> 6, lane = t & 63;
    int m = lane & 15, quad = lane >> 4;
    int p0 = blockIdx.x * 64;
    int o0 = wv * 32;
    float bb[2][4];
#pragma unroll
    for (int ot = 0; ot < 2; ot++)
#pragma unroll
        for (int reg = 0; reg < 4; reg++) bb[ot][reg] = bias[o0 + ot * 16 + quad * 4 + reg];
    floatx4 acc[2][4];
#pragma unroll
    for (int i = 0; i < 2; i++)
#pragma unroll
        for (int j = 0; j < 4; j++) acc[i][j] = (floatx4){0.f, 0.f, 0.f, 0.f};
#pragma unroll
    for (int kc = 0; kc < 4; kc++) {
        short8 a[2], b[4];
#pragma unroll
        for (int ot = 0; ot < 2; ot++)
            a[ot] = *(const short8*)(&Ws[(o0 + ot * 16 + m) * 136 + kc * 32 + quad * 8]);
#pragma unroll
        for (int pt = 0; pt < 4; pt++)
            b[pt] = *(const short8*)(A + (size_t)(p0 + pt * 16 + m) * CH + kc * 32 + quad * 8);
#pragma unroll
        for (int ot = 0; ot < 2; ot++)
#pragma unroll
            for (int pt = 0; pt < 4; pt++)
                acc[ot][pt] = __builtin_amdgcn_mfma_f32_16x16x32_bf16(a[ot], b[pt], acc[ot][pt], 0, 0, 0);
    }
    int tt = p0 / HWS;
    int hwb = p0 - tt * HWS;
#pragma unroll
    for (int ot = 0; ot < 2; ot++)
#pragma unroll
        for (int pt = 0; pt < 4; pt++)
#pragma unroll
            for (int reg = 0; reg < 4; reg++) {
                int o = o0 + ot * 16 + quad * 4 + reg;
                int hw = hwb + pt * 16 + m;
                out[((size_t)(tt * CH + o)) * HWS + hw] = acc[ot][pt][reg] + bb[ot][reg];
            }
}

extern "C" void kernel_launch(void* const* d_in, const int* in_sizes, int n_in,
                              void* d_out, int out_size, void* d_ws, size_t ws_size,
                              hipStream_t stream) {
    const float* vid    = (const float*)d_in[0];
    const float* wq_dw  = (const float*)d_in[1];
    const float* wq_pw  = (const float*)d_in[2];
    const float* bq     = (const float*)d_in[3];
    const float* wk_dw  = (const float*)d_in[4];
    const float* wk_pw  = (const float*)d_in[5];
    const float* bk     = (const float*)d_in[6];
    const float* wv_dw  = (const float*)d_in[7];
    const float* wv_pw  = (const float*)d_in[8];
    const float* bv     = (const float*)d_in[9];
    const float* proj_w = (const float*)d_in[10];
    const float* proj_b = (const float*)d_in[11];
    float* out = (float*)d_out;

    float* t_dw = (float*)d_ws;                       // 3*QC fp32  [sel][c][p]
    float* qkv  = t_dw + (size_t)3 * QC;              // 3*QC fp32  [p][c] q,k,v
    unsigned short* v_bf = (unsigned short*)(qkv + (size_t)3 * QC);  // QC bf16
    unsigned short* att_bf = v_bf;                    // alias: reused after vgemm

    dw_kernel<<<dim3(QTOT * CH / 256, 3), 256, 0, stream>>>(vid, wq_dw, wk_dw, wv_dw, t_dw);
    transcvt_v<<<dim3(QTOT / 64, 4), 256, 0, stream>>>(t_dw + (size_t)2 * QC, v_bf);
    gemm_qk_kernel<<<dim3(QTOT / 128, 4), 256, 0, stream>>>(t_dw, wq_pw, bq, wk_pw, bk, qkv);
    vgemm_mfma<<<QTOT / 64, 256, 0, stream>>>(v_bf, wv_pw, bv, qkv + (size_t)2 * QC);
    attn_kernel<<<dim3(TT * HH * (WW / SEG), 4), 256, 0, stream>>>(
        qkv, qkv + QC, qkv + (size_t)2 * QC, att_bf);
    proj_mfma<<<QTOT / 64, 256, 0, stream>>>(att_bf, proj_w, proj_b, out);
}

// Round 5
// 209.504 us; speedup vs baseline: 1.4708x; 1.0383x over previous
//
#include <hip/hip_runtime.h>
#include <math.h>

#define TT 2
#define CH 128
#define HH 96
#define WW 96
#define HWS 9216            // H*W
#define QTOT 18432          // T*H*W
#define QC (QTOT*CH)
#define HD 32
#define KTOP 16
#define SCALE 0.17677669529663687f  // 32^-0.5

#define SEG 16              // queries per attn block (one row segment)
#define PR 8                // patch rows
#define PC 23               // patch cols
#define PSTRIDE 36          // floats per patch pixel in LDS (16B-aligned, bank-spread)

typedef __attribute__((ext_vector_type(8))) short short8;
typedef __attribute__((ext_vector_type(4))) float floatx4;

__device__ __forceinline__ unsigned short f2bf(float f) {
    union { float f; unsigned u; } x; x.f = f;
    unsigned r = x.u + 0x7fffu + ((x.u >> 16) & 1u);
    return (unsigned short)(r >> 16);
}

__device__ __forceinline__ int refl(int x, int n) {
    x = x < 0 ? -x : x;
    return x >= n ? 2 * (n - 1) - x : x;
}

// ------ depthwise 3x3 (zero-pad SAME), all 3 sels in one pass, out fp32 [sel][c][p] -----
__global__ __launch_bounds__(256) void dw_kernel(
    const float* __restrict__ x,
    const float* __restrict__ wq, const float* __restrict__ wk, const float* __restrict__ wv,
    float* __restrict__ t_dw)
{
    int tid = blockIdx.x * 256 + threadIdx.x;
    int hw = tid % HWS;
    int cf = tid / HWS;
    int c = cf & (CH - 1);
    int tt = cf >> 7;
    int i = hw / WW, j = hw % WW;
    const float* xp = x + (size_t)(tt * CH + c) * HWS;
    float w0[9], w1[9], w2[9];
#pragma unroll
    for (int r = 0; r < 9; r++) { w0[r] = wq[c * 9 + r]; w1[r] = wk[c * 9 + r]; w2[r] = wv[c * 9 + r]; }
    float s0 = 0.f, s1 = 0.f, s2 = 0.f;
#pragma unroll
    for (int r = 0; r < 3; r++) {
        int ii = i + r - 1;
        if (ii < 0 || ii >= HH) continue;
#pragma unroll
        for (int ss = 0; ss < 3; ss++) {
            int jj = j + ss - 1;
            if (jj < 0 || jj >= WW) continue;
            float xv = xp[ii * WW + jj];
            s0 += xv * w0[r * 3 + ss];
            s1 += xv * w1[r * 3 + ss];
            s2 += xv * w2[r * 3 + ss];
        }
    }
    size_t o = (size_t)c * QTOT + tt * HWS + hw;
    t_dw[o] = s0;
    t_dw[QC + o] = s1;
    t_dw[2 * (size_t)QC + o] = s2;
}

// ---------------- transpose+convert v: [c][p] fp32 -> [p][c] bf16 ----------------
__global__ __launch_bounds__(256) void transcvt_v(
    const float* __restrict__ vd, unsigned short* __restrict__ vb)
{
    __shared__ float s[64][33];
    int t = threadIdx.x;
    int p0 = blockIdx.x * 64;
    int c0 = blockIdx.y * 32;
#pragma unroll
    for (int r = 0; r < 2; r++) {
        int lin = r * 256 + t;
        int c = lin >> 4;
        int pq = lin & 15;
        float4 v4 = *(const float4*)(vd + (size_t)(c0 + c) * QTOT + p0 + pq * 4);
        s[pq * 4 + 0][c] = v4.x; s[pq * 4 + 1][c] = v4.y;
        s[pq * 4 + 2][c] = v4.z; s[pq * 4 + 3][c] = v4.w;
    }
    __syncthreads();
    int p = t >> 2, cq = t & 3;
    unsigned u[8];
#pragma unroll
    for (int j = 0; j < 8; j++) u[j] = f2bf(s[p][cq * 8 + j]);
    uint4 pack;
    pack.x = u[0] | (u[1] << 16); pack.y = u[2] | (u[3] << 16);
    pack.z = u[4] | (u[5] << 16); pack.w = u[6] | (u[7] << 16);
    *(uint4*)(vb + (size_t)(p0 + p) * CH + c0 + cq * 8) = pack;
}

// ---------------- fp32 pointwise GEMM for q,k: 128px x 64o tiles, 8x4/thread ----------
__global__ __launch_bounds__(256) void gemm_qk_kernel(
    const float* __restrict__ t_dw,
    const float* __restrict__ wq_pw, const float* __restrict__ bq,
    const float* __restrict__ wk_pw, const float* __restrict__ bk,
    float* __restrict__ out)
{
    int sel = blockIdx.y >> 1;       // 0=q, 1=k
    int o0 = (blockIdx.y & 1) * 64;
    const float* Wg = sel == 0 ? wq_pw : wk_pw;
    const float* bg = sel == 0 ? bq : bk;
    const float* A = t_dw + (size_t)sel * QC;   // [c][p]
    float* O = out + (size_t)sel * QC;          // [p][c]
    float scale = sel == 0 ? SCALE : 1.f;

    __shared__ float A_s[32][128];
    __shared__ float Wt_s[32][68];   // [cc][oo]
    int tid = threadIdx.x;
    int o_grp = tid & 15;            // 4 o's
    int p_grp = tid >> 4;            // 8 p's
    int pbase = blockIdx.x * 128;
    float acc[8][4] = {};

    for (int c0 = 0; c0 < CH; c0 += 32) {
#pragma unroll
        for (int r = 0; r < 4; r++) {
            int lin = r * 256 + tid;
            int cc = lin >> 5, pq = lin & 31;
            *(float4*)&A_s[cc][pq * 4] =
                *(const float4*)&A[(size_t)(c0 + cc) * QTOT + pbase + pq * 4];
        }
#pragma unroll
        for (int r = 0; r < 2; r++) {
            int f = r * 256 + tid;
            int oo = f & 63, c4 = f >> 6;
            float4 w4 = *(const float4*)&Wg[(o0 + oo) * CH + c0 + c4 * 4];
            Wt_s[c4 * 4 + 0][oo] = w4.x;
            Wt_s[c4 * 4 + 1][oo] = w4.y;
            Wt_s[c4 * 4 + 2][oo] = w4.z;
            Wt_s[c4 * 4 + 3][oo] = w4.w;
        }
        __syncthreads();
#pragma unroll 8
        for (int cc = 0; cc < 32; cc++) {
            float4 a0 = *(const float4*)&A_s[cc][p_grp * 8];
            float4 a1 = *(const float4*)&A_s[cc][p_grp * 8 + 4];
            float4 b4 = *(const float4*)&Wt_s[cc][o_grp * 4];
            float a[8] = {a0.x, a0.y, a0.z, a0.w, a1.x, a1.y, a1.z, a1.w};
            float b[4] = {b4.x, b4.y, b4.z, b4.w};
#pragma unroll
            for (int i = 0; i < 8; i++)
#pragma unroll
                for (int kq = 0; kq < 4; kq++) acc[i][kq] += a[i] * b[kq];
        }
        __syncthreads();
    }
    float bb[4];
#pragma unroll
    for (int kq = 0; kq < 4; kq++) bb[kq] = bg[o0 + o_grp * 4 + kq];
#pragma unroll
    for (int i = 0; i < 8; i++) {
        int p = pbase + p_grp * 8 + i;
        float4 st;
        st.x = (acc[i][0] + bb[0]) * scale;
        st.y = (acc[i][1] + bb[1]) * scale;
        st.z = (acc[i][2] + bb[2]) * scale;
        st.w = (acc[i][3] + bb[3]) * scale;
        *(float4*)&O[(size_t)p * CH + o0 + o_grp * 4] = st;
    }
}

// ---------------- v pointwise via bf16 MFMA (64-px blocks) ----------------
__global__ __launch_bounds__(256) void vgemm_mfma(
    const unsigned short* __restrict__ A,   // v_bf [p][c] bf16
    const float* __restrict__ W,            // [o][c] fp32
    const float* __restrict__ bias,
    float* __restrict__ O)                  // fp32 [p][c]
{
    __shared__ unsigned short Ws[128 * 136];
    int t = threadIdx.x;
#pragma unroll
    for (int r = 0; r < 16; r++) {
        int lin = r * 256 + t;
        int o = lin >> 5, cq = lin & 31;
        float4 w4 = *(const float4*)(W + o * CH + cq * 4);
        uint2 pk;
        pk.x = f2bf(w4.x) | ((unsigned)f2bf(w4.y) << 16);
        pk.y = f2bf(w4.z) | ((unsigned)f2bf(w4.w) << 16);
        *(uint2*)(&Ws[o * 136 + cq * 4]) = pk;
    }
    __syncthreads();
    int wv = t >> 6, lane = t & 63;
    int m = lane & 15, quad = lane >> 4;
    int p0 = blockIdx.x * 64;
    int o0 = wv * 32;
    float bb[2];
#pragma unroll
    for (int ot = 0; ot < 2; ot++) bb[ot] = bias[o0 + ot * 16 + m];
    floatx4 acc[4][2];
#pragma unroll
    for (int i = 0; i < 4; i++)
#pragma unroll
        for (int j = 0; j < 2; j++) acc[i][j] = (floatx4){0.f, 0.f, 0.f, 0.f};
#pragma unroll
    for (int kc = 0; kc < 4; kc++) {
        short8 a[4], b[2];
#pragma unroll
        for (int pt = 0; pt < 4; pt++)
            a[pt] = *(const short8*)(A + (size_t)(p0 + pt * 16 + m) * CH + kc * 32 + quad * 8);
#pragma unroll
        for (int ot = 0; ot < 2; ot++)
            b[ot] = *(const short8*)(&Ws[(o0 + ot * 16 + m) * 136 + kc * 32 + quad * 8]);
#pragma unroll
        for (int pt = 0; pt < 4; pt++)
#pragma unroll
            for (int ot = 0; ot < 2; ot++)
                acc[pt][ot] = __builtin_amdgcn_mfma_f32_16x16x32_bf16(a[pt], b[ot], acc[pt][ot], 0, 0, 0);
    }
#pragma unroll
    for (int pt = 0; pt < 4; pt++)
#pragma unroll
        for (int ot = 0; ot < 2; ot++)
#pragma unroll
            for (int reg = 0; reg < 4; reg++) {
                int p = p0 + pt * 16 + quad * 4 + reg;
                O[(size_t)p * CH + o0 + ot * 16 + m] = acc[pt][ot][reg] + bb[ot];
            }
}

// ---------------- attention: LDS k-patch + early-exit radix select ----------------
__global__ __launch_bounds__(256) void attn_kernel(
    const float* __restrict__ q,   // [p][128] fp32
    const float* __restrict__ k,
    const float* __restrict__ v,
    unsigned short* __restrict__ att)  // [p][128] bf16
{
    __shared__ float kp[PR * PC * PSTRIDE];   // 26.5 KB
    int h = blockIdx.y;
    int seg = blockIdx.x;
    int qj0 = (seg % (WW / SEG)) * SEG;
    int qi = (seg / (WW / SEG)) % HH;
    int tt = seg / ((WW / SEG) * HH);
    int t = threadIdx.x;

    // stage reflected k patch: coalesced
#pragma unroll
    for (int r = 0; r < 6; r++) {
        int f = r * 256 + t;
        if (f < PR * PC * 8) {
            int pix = f >> 3, d4 = f & 7;
            int ci = pix / PC, cj = pix - ci * PC;
            int gi = refl(qi + ci - 4, HH);
            int gj = refl(qj0 + cj - 4, WW);
            int gp = tt * HWS + gi * WW + gj;
            *(float4*)(&kp[pix * PSTRIDE + d4 * 4]) =
                *(const float4*)(k + (size_t)gp * CH + h * HD + d4 * 4);
        }
    }
    __syncthreads();

    int wv = t >> 6, lane = t & 63;
    int ci = lane >> 3, cjo = lane & 7;
    int di = ci - 4, dj = cjo - 4;
    int rowoff = tt * HWS + refl(qi + di, HH) * WW;
    const int d = lane & (HD - 1);
    const unsigned long long below = (1ull << lane) - 1ull;

    for (int ql = wv * 4; ql < wv * 4 + 4; ql++) {
        int qj = qj0 + ql;
        int p = tt * HWS + qi * WW + qj;
        const float* qp = q + (size_t)p * CH + h * HD;
        const float* kr = &kp[(ci * PC + ql + cjo) * PSTRIDE];
        float dist = 0.f;
#pragma unroll
        for (int dd = 0; dd < 8; dd++) {
            float4 qv = *(const float4*)(qp + dd * 4);
            float4 kv = *(const float4*)(kr + dd * 4);
            dist += qv.x * kv.x + qv.y * kv.y + qv.z * kv.z + qv.w * kv.w;
        }
        int cpix = rowoff + refl(qj + dj, WW);

        // order-preserving uint key (desc select)
        unsigned u = __float_as_uint(dist);
        unsigned key = (u & 0x80000000u) ? ~u : (u | 0x80000000u);

        // radix-select top-16 set, wave-uniform early exit when class fills quota exactly
        unsigned long long selm;
        unsigned prefix = 0u;
        int need = KTOP;
        int bit = 31;
        bool resolved = false;
        for (; bit >= 0; --bit) {
            unsigned hi = (prefix >> bit) | 1u;
            unsigned long long b = __ballot((key >> bit) == hi);
            int cnt = __popcll(b);
            if (cnt == need) {                       // exact fill: done
                selm = __ballot((key >> bit) >= hi);
                resolved = true;
                break;
            }
            if (cnt > need) prefix |= (1u << bit);
            else need -= cnt;
        }
        if (!resolved) {                              // tie class straddles boundary
            bool isEq = (key == prefix);
            unsigned long long eqm = __ballot(isEq);
            int rk = __popcll(eqm & below);
            selm = __ballot((key > prefix) || (isEq && rk < need));
        }

        // softmax without shift: dists are O(1e-3), exp is exact-safe
        bool selb = (selm >> lane) & 1ull;
        float e = selb ? __expf(dist) : 0.f;

        // walk 16 selected lanes: scalar ctz + readlane, broadcast v rows
        float acc = 0.f, denom = 0.f;
        unsigned long long m0 = selm;
#pragma unroll
        for (int r = 0; r < KTOP; r++) {
            int s0 = __builtin_ctzll(m0); m0 &= m0 - 1ull;
            float a0 = __uint_as_float((unsigned)__builtin_amdgcn_readlane((int)__float_as_uint(e), s0));
            int p0 = __builtin_amdgcn_readlane(cpix, s0);
            denom += a0;
            acc += a0 * v[(size_t)p0 * CH + h * HD + d];
        }
        if (lane < HD)
            att[(size_t)p * CH + h * HD + lane] = f2bf(acc / denom);
    }
}

// ---------------- proj via bf16 MFMA (64-px blocks) ----------------
__global__ __launch_bounds__(256) void proj_mfma(
    const unsigned short* __restrict__ A,   // att_bf [p][c] bf16
    const float* __restrict__ W,            // proj_w [o][c] fp32
    const float* __restrict__ bias,
    float* __restrict__ out)                // NCHW fp32
{
    __shared__ unsigned short Ws[128 * 136];
    int t = threadIdx.x;
#pragma unroll
    for (int r = 0; r < 16; r++) {
        int lin = r * 256 + t;
        int o = lin >> 5, cq = lin & 31;
        float4 w4 = *(const float4*)(W + o * CH + cq * 4);
        uint2 pk;
        pk.x = f2bf(w4.x) | ((unsigned)f2bf(w4.y) << 16);
        pk.y = f2bf(w4.z) | ((unsigned)f2bf(w4.w) << 16);
        *(uint2*)(&Ws[o * 136 + cq * 4]) = pk;
    }
    __syncthreads();
    int wv = t >> 6, lane = t & 63;
    int m = lane & 15, quad = lane >> 4;
    int p0 = blockIdx.x * 64;
    int o0 = wv * 32;
    float bb[2][4];
#pragma unroll
    for (int ot = 0; ot < 2; ot++)
#pragma unroll
        for (int reg = 0; reg < 4; reg++) bb[ot][reg] = bias[o0 + ot * 16 + quad * 4 + reg];
    floatx4 acc[2][4];
#pragma unroll
    for (int i = 0; i < 2; i++)
#pragma unroll
        for (int j = 0; j < 4; j++) acc[i][j] = (floatx4){0.f, 0.f, 0.f, 0.f};
#pragma unroll
    for (int kc = 0; kc < 4; kc++) {
        short8 a[2], b[4];
#pragma unroll
        for (int ot = 0; ot < 2; ot++)
            a[ot] = *(const short8*)(&Ws[(o0 + ot * 16 + m) * 136 + kc * 32 + quad * 8]);
#pragma unroll
        for (int pt = 0; pt < 4; pt++)
            b[pt] = *(const short8*)(A + (size_t)(p0 + pt * 16 + m) * CH + kc * 32 + quad * 8);
#pragma unroll
        for (int ot = 0; ot < 2; ot++)
#pragma unroll
            for (int pt = 0; pt < 4; pt++)
                acc[ot][pt] = __builtin_amdgcn_mfma_f32_16x16x32_bf16(a[ot], b[pt], acc[ot][pt], 0, 0, 0);
    }
    int tt = p0 / HWS;
    int hwb = p0 - tt * HWS;
#pragma unroll
    for (int ot = 0; ot < 2; ot++)
#pragma unroll
        for (int pt = 0; pt < 4; pt++)
#pragma unroll
            for (int reg = 0; reg < 4; reg++) {
                int o = o0 + ot * 16 + quad * 4 + reg;
                int hw = hwb + pt * 16 + m;
                out[((size_t)(tt * CH + o)) * HWS + hw] = acc[ot][pt][reg] + bb[ot][reg];
            }
}

extern "C" void kernel_launch(void* const* d_in, const int* in_sizes, int n_in,
                              void* d_out, int out_size, void* d_ws, size_t ws_size,
                              hipStream_t stream) {
    const float* vid    = (const float*)d_in[0];
    const float* wq_dw  = (const float*)d_in[1];
    const float* wq_pw  = (const float*)d_in[2];
    const float* bq     = (const float*)d_in[3];
    const float* wk_dw  = (const float*)d_in[4];
    const float* wk_pw  = (const float*)d_in[5];
    const float* bk     = (const float*)d_in[6];
    const float* wv_dw  = (const float*)d_in[7];
    const float* wv_pw  = (const float*)d_in[8];
    const float* bv     = (const float*)d_in[9];
    const float* proj_w = (const float*)d_in[10];
    const float* proj_b = (const float*)d_in[11];
    float* out = (float*)d_out;

    float* t_dw = (float*)d_ws;                       // 3*QC fp32  [sel][c][p]
    float* qkv  = t_dw + (size_t)3 * QC;              // 3*QC fp32  [p][c] q,k,v
    unsigned short* v_bf = (unsigned short*)(qkv + (size_t)3 * QC);  // QC bf16
    unsigned short* att_bf = v_bf;                    // alias: reused after vgemm

    dw_kernel<<<QTOT * CH / 256, 256, 0, stream>>>(vid, wq_dw, wk_dw, wv_dw, t_dw);
    transcvt_v<<<dim3(QTOT / 64, 4), 256, 0, stream>>>(t_dw + (size_t)2 * QC, v_bf);
    gemm_qk_kernel<<<dim3(QTOT / 128, 4), 256, 0, stream>>>(t_dw, wq_pw, bq, wk_pw, bk, qkv);
    vgemm_mfma<<<QTOT / 64, 256, 0, stream>>>(v_bf, wv_pw, bv, qkv + (size_t)2 * QC);
    attn_kernel<<<dim3(TT * HH * (WW / SEG), 4), 256, 0, stream>>>(
        qkv, qkv + QC, qkv + (size_t)2 * QC, att_bf);
    proj_mfma<<<QTOT / 64, 256, 0, stream>>>(att_bf, proj_w, proj_b, out);
}

// Round 6
// 205.755 us; speedup vs baseline: 1.4976x; 1.0182x over previous
//
#include <hip/hip_runtime.h>
#include <math.h>

#define TT 2
#define CH 128
#define HH 96
#define WW 96
#define HWS 9216            // H*W
#define QTOT 18432          // T*H*W
#define QC (QTOT*CH)
#define HD 32
#define KTOP 16
#define SCALE 0.17677669529663687f  // 32^-0.5

#define SEG 16              // queries per attn block (one row segment)
#define PR 8                // patch rows
#define PC 23               // patch cols
#define PSTRIDE 36          // floats per patch pixel in LDS

typedef __attribute__((ext_vector_type(8))) short short8;
typedef __attribute__((ext_vector_type(4))) float floatx4;

__device__ __forceinline__ unsigned short f2bf(float f) {
    union { float f; unsigned u; } x; x.f = f;
    unsigned r = x.u + 0x7fffu + ((x.u >> 16) & 1u);
    return (unsigned short)(r >> 16);
}
__device__ __forceinline__ float bf2f(unsigned short h) {
    return __uint_as_float(((unsigned)h) << 16);
}

__device__ __forceinline__ int refl(int x, int n) {
    x = x < 0 ? -x : x;
    return x >= n ? 2 * (n - 1) - x : x;
}

// ------ depthwise 3x3 (zero-pad SAME), all 3 sels in one pass, out fp32 [sel][c][p] -----
__global__ __launch_bounds__(256) void dw_kernel(
    const float* __restrict__ x,
    const float* __restrict__ wq, const float* __restrict__ wk, const float* __restrict__ wv,
    float* __restrict__ t_dw)
{
    int tid = blockIdx.x * 256 + threadIdx.x;
    int hw = tid % HWS;
    int cf = tid / HWS;
    int c = cf & (CH - 1);
    int tt = cf >> 7;
    int i = hw / WW, j = hw % WW;
    const float* xp = x + (size_t)(tt * CH + c) * HWS;
    float w0[9], w1[9], w2[9];
#pragma unroll
    for (int r = 0; r < 9; r++) { w0[r] = wq[c * 9 + r]; w1[r] = wk[c * 9 + r]; w2[r] = wv[c * 9 + r]; }
    float s0 = 0.f, s1 = 0.f, s2 = 0.f;
#pragma unroll
    for (int r = 0; r < 3; r++) {
        int ii = i + r - 1;
        if (ii < 0 || ii >= HH) continue;
#pragma unroll
        for (int ss = 0; ss < 3; ss++) {
            int jj = j + ss - 1;
            if (jj < 0 || jj >= WW) continue;
            float xv = xp[ii * WW + jj];
            s0 += xv * w0[r * 3 + ss];
            s1 += xv * w1[r * 3 + ss];
            s2 += xv * w2[r * 3 + ss];
        }
    }
    size_t o = (size_t)c * QTOT + tt * HWS + hw;
    t_dw[o] = s0;
    t_dw[QC + o] = s1;
    t_dw[2 * (size_t)QC + o] = s2;
}

// ------ transpose+convert: [c][p] fp32 -> [p][c] bf16; q,k get hi+lo split, v single ----
__global__ __launch_bounds__(256) void transcvt(
    const float* __restrict__ t_dw,
    unsigned short* __restrict__ qk_hi,   // [2][p][c]
    unsigned short* __restrict__ qk_lo,   // [2][p][c]
    unsigned short* __restrict__ v_bf)    // [p][c]
{
    __shared__ float s[64][33];
    int sel = blockIdx.z;
    const float* vd = t_dw + (size_t)sel * QC;
    int t = threadIdx.x;
    int p0 = blockIdx.x * 64;
    int c0 = blockIdx.y * 32;
#pragma unroll
    for (int r = 0; r < 2; r++) {
        int lin = r * 256 + t;
        int c = lin >> 4;
        int pq = lin & 15;
        float4 v4 = *(const float4*)(vd + (size_t)(c0 + c) * QTOT + p0 + pq * 4);
        s[pq * 4 + 0][c] = v4.x; s[pq * 4 + 1][c] = v4.y;
        s[pq * 4 + 2][c] = v4.z; s[pq * 4 + 3][c] = v4.w;
    }
    __syncthreads();
    int p = t >> 2, cq = t & 3;
    unsigned uh[8], ul[8];
#pragma unroll
    for (int j = 0; j < 8; j++) {
        float x = s[p][cq * 8 + j];
        unsigned short h = f2bf(x);
        uh[j] = h;
        ul[j] = f2bf(x - bf2f(h));
    }
    uint4 ph, pl;
    ph.x = uh[0] | (uh[1] << 16); ph.y = uh[2] | (uh[3] << 16);
    ph.z = uh[4] | (uh[5] << 16); ph.w = uh[6] | (uh[7] << 16);
    size_t off = (size_t)(p0 + p) * CH + c0 + cq * 8;
    if (sel < 2) {
        pl.x = ul[0] | (ul[1] << 16); pl.y = ul[2] | (ul[3] << 16);
        pl.z = ul[4] | (ul[5] << 16); pl.w = ul[6] | (ul[7] << 16);
        *(uint4*)(qk_hi + (size_t)sel * QC + off) = ph;
        *(uint4*)(qk_lo + (size_t)sel * QC + off) = pl;
    } else {
        *(uint4*)(v_bf + off) = ph;
    }
}

// ------ q,k pointwise via bf16x3 MFMA (fp32-emulating split): O = (A W^T + b) * scale ---
__global__ __launch_bounds__(256) void qk_mfma(
    const unsigned short* __restrict__ Ahi,   // [2][p][c]
    const unsigned short* __restrict__ Alo,
    const float* __restrict__ wq_pw, const float* __restrict__ wk_pw,
    const float* __restrict__ bq, const float* __restrict__ bk,
    float* __restrict__ t_dw)                 // out: q -> t_dw[0], k -> t_dw[1] ([p][c])
{
    int sel = blockIdx.y;
    const float* W = sel ? wk_pw : wq_pw;
    const float* bias = sel ? bk : bq;
    float scale = sel ? 1.f : SCALE;
    const unsigned short* ah = Ahi + (size_t)sel * QC;
    const unsigned short* al = Alo + (size_t)sel * QC;
    float* O = t_dw + (size_t)sel * QC;

    __shared__ unsigned short Wh[128 * 136];
    __shared__ unsigned short Wl[128 * 136];
    int t = threadIdx.x;
#pragma unroll
    for (int r = 0; r < 16; r++) {
        int lin = r * 256 + t;
        int o = lin >> 5, cq = lin & 31;
        float4 w4 = *(const float4*)(W + o * CH + cq * 4);
        unsigned short hx = f2bf(w4.x), hy = f2bf(w4.y), hz = f2bf(w4.z), hw = f2bf(w4.w);
        unsigned short lx = f2bf(w4.x - bf2f(hx)), ly = f2bf(w4.y - bf2f(hy));
        unsigned short lz = f2bf(w4.z - bf2f(hz)), lw = f2bf(w4.w - bf2f(hw));
        uint2 pk;
        pk.x = hx | ((unsigned)hy << 16); pk.y = hz | ((unsigned)hw << 16);
        *(uint2*)(&Wh[o * 136 + cq * 4]) = pk;
        pk.x = lx | ((unsigned)ly << 16); pk.y = lz | ((unsigned)lw << 16);
        *(uint2*)(&Wl[o * 136 + cq * 4]) = pk;
    }
    __syncthreads();
    int wv = t >> 6, lane = t & 63;
    int m = lane & 15, quad = lane >> 4;
    int p0 = blockIdx.x * 64;
    int o0 = wv * 32;
    float bb[2];
#pragma unroll
    for (int ot = 0; ot < 2; ot++) bb[ot] = bias[o0 + ot * 16 + m];
    floatx4 acc[4][2];
#pragma unroll
    for (int i = 0; i < 4; i++)
#pragma unroll
        for (int j = 0; j < 2; j++) acc[i][j] = (floatx4){0.f, 0.f, 0.f, 0.f};
#pragma unroll
    for (int kc = 0; kc < 4; kc++) {
        short8 avh[4], avl[4], bh[2], bl[2];
#pragma unroll
        for (int pt = 0; pt < 4; pt++) {
            size_t base = (size_t)(p0 + pt * 16 + m) * CH + kc * 32 + quad * 8;
            avh[pt] = *(const short8*)(ah + base);
            avl[pt] = *(const short8*)(al + base);
        }
#pragma unroll
        for (int ot = 0; ot < 2; ot++) {
            int lidx = (o0 + ot * 16 + m) * 136 + kc * 32 + quad * 8;
            bh[ot] = *(const short8*)(&Wh[lidx]);
            bl[ot] = *(const short8*)(&Wl[lidx]);
        }
#pragma unroll
        for (int pt = 0; pt < 4; pt++)
#pragma unroll
            for (int ot = 0; ot < 2; ot++) {
                acc[pt][ot] = __builtin_amdgcn_mfma_f32_16x16x32_bf16(avh[pt], bh[ot], acc[pt][ot], 0, 0, 0);
                acc[pt][ot] = __builtin_amdgcn_mfma_f32_16x16x32_bf16(avh[pt], bl[ot], acc[pt][ot], 0, 0, 0);
                acc[pt][ot] = __builtin_amdgcn_mfma_f32_16x16x32_bf16(avl[pt], bh[ot], acc[pt][ot], 0, 0, 0);
            }
    }
#pragma unroll
    for (int pt = 0; pt < 4; pt++)
#pragma unroll
        for (int ot = 0; ot < 2; ot++)
#pragma unroll
            for (int reg = 0; reg < 4; reg++) {
                int p = p0 + pt * 16 + quad * 4 + reg;
                O[(size_t)p * CH + o0 + ot * 16 + m] = (acc[pt][ot][reg] + bb[ot]) * scale;
            }
}

// ---------------- v pointwise via bf16 MFMA (64-px blocks) ----------------
__global__ __launch_bounds__(256) void vgemm_mfma(
    const unsigned short* __restrict__ A,   // v_bf [p][c] bf16
    const float* __restrict__ W,            // [o][c] fp32
    const float* __restrict__ bias,
    float* __restrict__ O)                  // fp32 [p][c]
{
    __shared__ unsigned short Ws[128 * 136];
    int t = threadIdx.x;
#pragma unroll
    for (int r = 0; r < 16; r++) {
        int lin = r * 256 + t;
        int o = lin >> 5, cq = lin & 31;
        float4 w4 = *(const float4*)(W + o * CH + cq * 4);
        uint2 pk;
        pk.x = f2bf(w4.x) | ((unsigned)f2bf(w4.y) << 16);
        pk.y = f2bf(w4.z) | ((unsigned)f2bf(w4.w) << 16);
        *(uint2*)(&Ws[o * 136 + cq * 4]) = pk;
    }
    __syncthreads();
    int wv = t >> 6, lane = t & 63;
    int m = lane & 15, quad = lane >> 4;
    int p0 = blockIdx.x * 64;
    int o0 = wv * 32;
    float bb[2];
#pragma unroll
    for (int ot = 0; ot < 2; ot++) bb[ot] = bias[o0 + ot * 16 + m];
    floatx4 acc[4][2];
#pragma unroll
    for (int i = 0; i < 4; i++)
#pragma unroll
        for (int j = 0; j < 2; j++) acc[i][j] = (floatx4){0.f, 0.f, 0.f, 0.f};
#pragma unroll
    for (int kc = 0; kc < 4; kc++) {
        short8 a[4], b[2];
#pragma unroll
        for (int pt = 0; pt < 4; pt++)
            a[pt] = *(const short8*)(A + (size_t)(p0 + pt * 16 + m) * CH + kc * 32 + quad * 8);
#pragma unroll
        for (int ot = 0; ot < 2; ot++)
            b[ot] = *(const short8*)(&Ws[(o0 + ot * 16 + m) * 136 + kc * 32 + quad * 8]);
#pragma unroll
        for (int pt = 0; pt < 4; pt++)
#pragma unroll
            for (int ot = 0; ot < 2; ot++)
                acc[pt][ot] = __builtin_amdgcn_mfma_f32_16x16x32_bf16(a[pt], b[ot], acc[pt][ot], 0, 0, 0);
    }
#pragma unroll
    for (int pt = 0; pt < 4; pt++)
#pragma unroll
        for (int ot = 0; ot < 2; ot++)
#pragma unroll
            for (int reg = 0; reg < 4; reg++) {
                int p = p0 + pt * 16 + quad * 4 + reg;
                O[(size_t)p * CH + o0 + ot * 16 + m] = acc[pt][ot][reg] + bb[ot];
            }
}

// ---------------- attention: LDS k-patch + fixed-32 unrolled radix select -------------
__global__ __launch_bounds__(256) void attn_kernel(
    const float* __restrict__ q,   // [p][128] fp32
    const float* __restrict__ k,
    const float* __restrict__ v,
    unsigned short* __restrict__ att)  // [p][128] bf16
{
    __shared__ float kp[PR * PC * PSTRIDE];   // 26.5 KB
    int h = blockIdx.y;
    int seg = blockIdx.x;
    int qj0 = (seg % (WW / SEG)) * SEG;
    int qi = (seg / (WW / SEG)) % HH;
    int tt = seg / ((WW / SEG) * HH);
    int t = threadIdx.x;

    // stage reflected k patch: coalesced
#pragma unroll
    for (int r = 0; r < 6; r++) {
        int f = r * 256 + t;
        if (f < PR * PC * 8) {
            int pix = f >> 3, d4 = f & 7;
            int ci = pix / PC, cj = pix - ci * PC;
            int gi = refl(qi + ci - 4, HH);
            int gj = refl(qj0 + cj - 4, WW);
            int gp = tt * HWS + gi * WW + gj;
            *(float4*)(&kp[pix * PSTRIDE + d4 * 4]) =
                *(const float4*)(k + (size_t)gp * CH + h * HD + d4 * 4);
        }
    }
    __syncthreads();

    int wv = t >> 6, lane = t & 63;
    int ci = lane >> 3, cjo = lane & 7;
    int di = ci - 4, dj = cjo - 4;
    int rowoff = tt * HWS + refl(qi + di, HH) * WW;
    const int d = lane & (HD - 1);
    const unsigned long long below = (1ull << lane) - 1ull;

    for (int ql = wv * 4; ql < wv * 4 + 4; ql++) {
        int qj = qj0 + ql;
        int p = tt * HWS + qi * WW + qj;
        const float* qp = q + (size_t)p * CH + h * HD;
        const float* kr = &kp[(ci * PC + ql + cjo) * PSTRIDE];
        float dist = 0.f;
#pragma unroll
        for (int dd = 0; dd < 8; dd++) {
            float4 qv = *(const float4*)(qp + dd * 4);
            float4 kv = *(const float4*)(kr + dd * 4);
            dist += qv.x * kv.x + qv.y * kv.y + qv.z * kv.z + qv.w * kv.w;
        }
        int cpix = rowoff + refl(qj + dj, WW);

        // order-preserving uint key (desc select)
        unsigned u = __float_as_uint(dist);
        unsigned key = (u & 0x80000000u) ? ~u : (u | 0x80000000u);

        // fixed-32 branch-free radix select of the 16th-largest key
        unsigned prefix = 0u;
        int need = KTOP;
#pragma unroll
        for (int bit = 31; bit >= 0; --bit) {
            unsigned hi = (prefix >> bit) | 1u;
            unsigned long long b = __ballot((key >> bit) == hi);
            int cnt = __popcll(b);
            bool take = cnt >= need;
            prefix = take ? (prefix | (1u << bit)) : prefix;
            need = take ? need : need - cnt;
        }
        // selection set: key > kth, plus first `need` of tie class by lane asc
        bool isEq = (key == prefix);
        unsigned long long eqm = __ballot(isEq);
        int rk = __popcll(eqm & below);
        bool selb = (key > prefix) || (isEq && rk < need);
        unsigned long long selm = __ballot(selb);

        // softmax without shift: dists are O(1e-3), exp is exact-safe
        float e = selb ? __expf(dist) : 0.f;

        // walk 16 selected lanes: scalar ctz + readlane, broadcast v rows
        float acc = 0.f, denom = 0.f;
        unsigned long long m0 = selm;
#pragma unroll
        for (int r = 0; r < KTOP; r++) {
            int s0 = __builtin_ctzll(m0); m0 &= m0 - 1ull;
            float a0 = __uint_as_float((unsigned)__builtin_amdgcn_readlane((int)__float_as_uint(e), s0));
            int p0 = __builtin_amdgcn_readlane(cpix, s0);
            denom += a0;
            acc += a0 * v[(size_t)p0 * CH + h * HD + d];
        }
        if (lane < HD)
            att[(size_t)p * CH + h * HD + lane] = f2bf(acc / denom);
    }
}

// ---------------- proj via bf16 MFMA (64-px blocks) ----------------
__global__ __launch_bounds__(256) void proj_mfma(
    const unsigned short* __restrict__ A,   // att_bf [p][c] bf16
    const float* __restrict__ W,            // proj_w [o][c] fp32
    const float* __restrict__ bias,
    float* __restrict__ out)                // NCHW fp32
{
    __shared__ unsigned short Ws[128 * 136];
    int t = threadIdx.x;
#pragma unroll
    for (int r = 0; r < 16; r++) {
        int lin = r * 256 + t;
        int o = lin >> 5, cq = lin & 31;
        float4 w4 = *(const float4*)(W + o * CH + cq * 4);
        uint2 pk;
        pk.x = f2bf(w4.x) | ((unsigned)f2bf(w4.y) << 16);
        pk.y = f2bf(w4.z) | ((unsigned)f2bf(w4.w) << 16);
        *(uint2*)(&Ws[o * 136 + cq * 4]) = pk;
    }
    __syncthreads();
    int wv = t >> 6, lane = t & 63;
    int m = lane & 15, quad = lane >> 4;
    int p0 = blockIdx.x * 64;
    int o0 = wv * 32;
    float bb[2][4];
#pragma unroll
    for (int ot = 0; ot < 2; ot++)
#pragma unroll
        for (int reg = 0; reg < 4; reg++) bb[ot][reg] = bias[o0 + ot * 16 + quad * 4 + reg];
    floatx4 acc[2][4];
#pragma unroll
    for (int i = 0; i < 2; i++)
#pragma unroll
        for (int j = 0; j < 4; j++) acc[i][j] = (floatx4){0.f, 0.f, 0.f, 0.f};
#pragma unroll
    for (int kc = 0; kc < 4; kc++) {
        short8 a[2], b[4];
#pragma unroll
        for (int ot = 0; ot < 2; ot++)
            a[ot] = *(const short8*)(&Ws[(o0 + ot * 16 + m) * 136 + kc * 32 + quad * 8]);
#pragma unroll
        for (int pt = 0; pt < 4; pt++)
            b[pt] = *(const short8*)(A + (size_t)(p0 + pt * 16 + m) * CH + kc * 32 + quad * 8);
#pragma unroll
        for (int ot = 0; ot < 2; ot++)
#pragma unroll
            for (int pt = 0; pt < 4; pt++)
                acc[ot][pt] = __builtin_amdgcn_mfma_f32_16x16x32_bf16(a[ot], b[pt], acc[ot][pt], 0, 0, 0);
    }
    int tt = p0 / HWS;
    int hwb = p0 - tt * HWS;
#pragma unroll
    for (int ot = 0; ot < 2; ot++)
#pragma unroll
        for (int pt = 0; pt < 4; pt++)
#pragma unroll
            for (int reg = 0; reg < 4; reg++) {
                int o = o0 + ot * 16 + quad * 4 + reg;
                int hw = hwb + pt * 16 + m;
                out[((size_t)(tt * CH + o)) * HWS + hw] = acc[ot][pt][reg] + bb[ot][reg];
            }
}

extern "C" void kernel_launch(void* const* d_in, const int* in_sizes, int n_in,
                              void* d_out, int out_size, void* d_ws, size_t ws_size,
                              hipStream_t stream) {
    const float* vid    = (const float*)d_in[0];
    const float* wq_dw  = (const float*)d_in[1];
    const float* wq_pw  = (const float*)d_in[2];
    const float* bq     = (const float*)d_in[3];
    const float* wk_dw  = (const float*)d_in[4];
    const float* wk_pw  = (const float*)d_in[5];
    const float* bk     = (const float*)d_in[6];
    const float* wv_dw  = (const float*)d_in[7];
    const float* wv_pw  = (const float*)d_in[8];
    const float* bv     = (const float*)d_in[9];
    const float* proj_w = (const float*)d_in[10];
    const float* proj_b = (const float*)d_in[11];
    float* out = (float*)d_out;

    // workspace (61.3 MB):
    //   t_dw  : 3*QC fp32 [sel][c][p]; q,k fp32 [p][c] outputs OVERWRITE [0],[1] (dead after transcvt)
    //   v_f32 : QC fp32 [p][c]
    //   qk_hi : 2*QC bf16, qk_lo : 2*QC bf16
    //   v_bf  : QC bf16 (aliased as att_bf after vgemm consumes it)
    float* t_dw = (float*)d_ws;
    float* v_f32 = t_dw + (size_t)3 * QC;
    unsigned short* qk_hi = (unsigned short*)(v_f32 + (size_t)QC);
    unsigned short* qk_lo = qk_hi + (size_t)2 * QC;
    unsigned short* v_bf = qk_lo + (size_t)2 * QC;
    unsigned short* att_bf = v_bf;

    dw_kernel<<<QTOT * CH / 256, 256, 0, stream>>>(vid, wq_dw, wk_dw, wv_dw, t_dw);
    transcvt<<<dim3(QTOT / 64, 4, 3), 256, 0, stream>>>(t_dw, qk_hi, qk_lo, v_bf);
    qk_mfma<<<dim3(QTOT / 64, 2), 256, 0, stream>>>(qk_hi, qk_lo, wq_pw, wk_pw, bq, bk, t_dw);
    vgemm_mfma<<<QTOT / 64, 256, 0, stream>>>(v_bf, wv_pw, bv, v_f32);
    attn_kernel<<<dim3(TT * HH * (WW / SEG), 4), 256, 0, stream>>>(
        t_dw, t_dw + (size_t)QC, v_f32, att_bf);
    proj_mfma<<<QTOT / 64, 256, 0, stream>>>(att_bf, proj_w, proj_b, out);
}